// Round 8
// baseline (2816.890 us; speedup 1.0000x reference)
//
#include <hip/hip_runtime.h>
#include <math.h>

#define EPS 1e-5f

// ---------------- float offsets in ws ----------------
#define OFF_A  0u          // conv1 out [1024][8][28][11][11] = 27,754,496 (dead after conv2)
#define OFF_X0 0u          // tokens x  [1024][81][64] = 5,308,416 (written after A dead)
#define OFF_Y  31850496u   // y [1024][81][64]; conv2 partial A during conv stage
#define OFF_PA 31850496u   // conv2 partial (ci 0..111)   -- dead before fa writes OFF_Y
#define OFF_PB 37158912u   // conv2 partial (ci 112..223)
#define OFF_B  47775744u   // conv2 out [1024][64][81] = 5,308,416
#define OFF_P  53084160u   // partials  131,072
#define OFF_ST 53215232u   // scale1[8] shift1[8] scale2[64] shift2[64]

// ---------------- kd1: conv3d + bias -> A ----------------
__global__ __launch_bounds__(256) void kd1_conv1(const float* X, const float* c3w,
                                                 const float* c3b, float* ws) {
  int idx = blockIdx.x * 256 + threadIdx.x;
  if (idx >= 27754496) return;
  int pos = idx;
  int w = pos % 11; pos /= 11;
  int h = pos % 11; pos /= 11;
  int dd = pos % 28; pos /= 28;
  int o1 = pos % 8;
  int b = pos / 8;
  const float* Xb = X + (size_t)b * 5070;
  float a = c3b[o1];
#pragma unroll
  for (int kd = 0; kd < 3; ++kd)
#pragma unroll
    for (int kh = 0; kh < 3; ++kh)
#pragma unroll
      for (int kw = 0; kw < 3; ++kw)
        a = fmaf(Xb[(dd+kd)*169 + (h+kh)*13 + (w+kw)],
                 c3w[o1*27 + kd*9 + kh*3 + kw], a);
  ws[OFF_A + idx] = a;
}

// ---------------- kd2: BN1 partial sums per (b, o1) ----------------
__global__ __launch_bounds__(256) void kd2_bn1part(const float* ws_in, float* ws) {
  __shared__ float sS[256], sQ[256];
  int blk = blockIdx.x;               // b*8 + o1
  int tid = threadIdx.x;
  const float* Ab = ws_in + OFF_A + (size_t)blk * 3388;
  float S = 0.f, Q = 0.f;
  for (int i = tid; i < 3388; i += 256) {
    float v = Ab[i];
    S += v; Q += v * v;
  }
  sS[tid] = S; sQ[tid] = Q;
  __syncthreads();
  for (int st = 128; st > 0; st >>= 1) {
    if (tid < st) { sS[tid] += sS[tid+st]; sQ[tid] += sQ[tid+st]; }
    __syncthreads();
  }
  if (tid == 0) {
    ws[OFF_P + blk*2]     = sS[0];
    ws[OFF_P + blk*2 + 1] = sQ[0];
  }
}

// ---------------- kd3: BN1 finalize ----------------
__global__ void kd3_bn1fin(float* ws, const float* bn3g, const float* bn3b) {
  int t = threadIdx.x;
  if (t < 8) {
    float S = 0.f, Q = 0.f;
    for (int j = t; j < 8192; j += 8) {
      S += ws[OFF_P + j*2];
      Q += ws[OFF_P + j*2 + 1];
    }
    float n = 3469312.f;
    float mean = S / n;
    float var = Q / n - mean * mean;
    float sc = bn3g[t] * rsqrtf(var + EPS);
    ws[OFF_ST + t]     = sc;
    ws[OFF_ST + 8 + t] = bn3b[t] - mean * sc;
  }
}

// ---------------- kd5: conv2 split-K, per-(batch,half) LDS-tiled ----------------
__global__ __launch_bounds__(192) void kd5_conv2(const float* ws_in, const float* c2w,
                                                 float* ws) {
  __shared__ float wl[4752];    // [kk 9][ciL 8][oc pad 66]
  __shared__ float inl[1056];   // [ciL 8][11 rows x 12]
  __shared__ float bn1[16];
  int tid = threadIdx.x;
  int b = blockIdx.x;
  int half = blockIdx.y;        // 0: ci 0..111, 1: ci 112..223
  int o = tid / 3, q = tid - o*3;
  if (tid < 16) bn1[tid] = ws_in[OFF_ST + tid];
  const float* Ab = ws_in + OFF_A + (size_t)b * 27104;   // [224][11][11]
  float acc[3][9];
#pragma unroll
  for (int ir = 0; ir < 3; ++ir)
#pragma unroll
    for (int x = 0; x < 9; ++x) acc[ir][x] = 0.f;

  for (int c14 = 0; c14 < 14; ++c14) {
    int cc = half*14 + c14;
    __syncthreads();
#pragma unroll
    for (int it = 0; it < 24; ++it) {
      int j = tid + 192*it;
      int og = j / 72, r = j - og*72;
      int ciL = r / 9, kk = r - ciL*9;
      wl[kk*528 + ciL*66 + og] = c2w[(og*224 + cc*8 + ciL)*9 + kk];
    }
#pragma unroll
    for (int it = 0; it < 6; ++it) {
      int e = tid + 192*it;
      if (e < 968) {
        int ciL = e / 121, pos = e - ciL*121;
        int h = pos / 11, w = pos - h*11;
        int ci = cc*8 + ciL;
        int o1 = ci / 28;
        float raw = Ab[(size_t)ci*121 + pos];
        float v = bn1[o1]*raw + bn1[8+o1];
        inl[ciL*132 + h*12 + w] = fmaxf(v, 0.f);
      }
    }
    __syncthreads();
    for (int ciL = 0; ciL < 8; ++ciL) {
      float rr[5][12];
#pragma unroll
      for (int r5 = 0; r5 < 5; ++r5) {
        const float4* rp = (const float4*)(inl + ciL*132 + (q*3 + r5)*12);
        float4 A4 = rp[0], B4 = rp[1], C4 = rp[2];
        rr[r5][0]=A4.x; rr[r5][1]=A4.y; rr[r5][2]=A4.z; rr[r5][3]=A4.w;
        rr[r5][4]=B4.x; rr[r5][5]=B4.y; rr[r5][6]=B4.z; rr[r5][7]=B4.w;
        rr[r5][8]=C4.x; rr[r5][9]=C4.y; rr[r5][10]=C4.z; rr[r5][11]=C4.w;
      }
#pragma unroll
      for (int ki = 0; ki < 3; ++ki) {
#pragma unroll
        for (int kj = 0; kj < 3; ++kj) {
          float wv = wl[(ki*3+kj)*528 + ciL*66 + o];
#pragma unroll
          for (int ir = 0; ir < 3; ++ir)
#pragma unroll
            for (int x = 0; x < 9; ++x)
              acc[ir][x] = fmaf(rr[ir+ki][x+kj], wv, acc[ir][x]);
        }
      }
    }
  }
  float* dst = ws + (half ? OFF_PB : OFF_PA) + ((size_t)b*64 + o)*81;
#pragma unroll
  for (int ir = 0; ir < 3; ++ir)
#pragma unroll
    for (int x = 0; x < 9; ++x)
      dst[(q*3+ir)*9 + x] = acc[ir][x];
}

// ---------------- kd6: merge conv2 halves + bias -> B; BN2 partials ----------------
__global__ void kd6_bn2part(const float* ws_in, float* ws, const float* c2b) {
  int b = blockIdx.x, t = threadIdx.x;  // t = channel (64 threads)
  const float* pa = ws_in + OFF_PA + (size_t)b * 5184 + t * 81;
  const float* pb = ws_in + OFF_PB + (size_t)b * 5184 + t * 81;
  float* Bb = ws + OFF_B + (size_t)b * 5184 + t * 81;
  float bias = c2b[t];
  float S = 0.f, Q = 0.f;
  for (int s = 0; s < 81; ++s) {
    float v = pa[s] + pb[s] + bias;
    Bb[s] = v;
    S += v; Q += v * v;
  }
  ws[OFF_P + b*128 + t]      = S;
  ws[OFF_P + b*128 + 64 + t] = Q;
}

// ---------------- kd7: BN2 finalize ----------------
__global__ void kd7_bn2fin(float* ws, const float* bn2g, const float* bn2b) {
  int t = threadIdx.x;
  float S = 0.f, Q = 0.f;
  for (int b = 0; b < 1024; ++b) {
    S += ws[OFF_P + b*128 + t];
    Q += ws[OFF_P + b*128 + 64 + t];
  }
  float n = 82944.f;
  float mean = S / n;
  float var = Q / n - mean * mean;
  float sc = bn2g[t] * rsqrtf(var + EPS);
  ws[OFF_ST + 16 + t] = sc;
  ws[OFF_ST + 80 + t] = bn2b[t] - mean * sc;
}

// ---------------- kd8: BN2 apply + relu + transpose -> X0 [b][s][64] ----------------
__global__ __launch_bounds__(256) void kd8_tokens(float* ws) {
  int idx = blockIdx.x * 256 + threadIdx.x;
  if (idx >= 5308416) return;
  int o = idx % 64;
  int s = (idx / 64) % 81;
  int b = idx / 5184;
  float v = ws[OFF_ST + 16 + o] * ws[OFF_B + (size_t)b*5184 + o*81 + s] + ws[OFF_ST + 80 + o];
  ws[OFF_X0 + idx] = fmaxf(v, 0.f);
}

// ---------------- fa_layer v3: no Z buffer (G in regs, gn in dead q-slots), 69.5 KB LDS ----------------
__global__ __launch_bounds__(256) void fa_layer(const float* ws_in, float* ws,
    const float* wq, const float* wk, const float* wv, const float* wgp, const float* wop,
    const float* ln1g, const float* ln1b, const float* gng, const float* gnb, int l)
{
  __shared__ __align__(16) float H[81*68];
  __shared__ float P0[81*33];   // pair0 q -> gn(heads 0,1)
  __shared__ float P1[81*33];   // pair0 k -> pair1 q -> gn(heads 2,3)
  __shared__ float P2[81*33];   // pair0 v -> pair1 k
  __shared__ float P3[81*33];   // pair1 v
  __shared__ float Wst[1024];
  __shared__ float muv[81], rsd[81];
  const int tid = threadIdx.x;
  const int b = blockIdx.x;
  const float* xg = ws_in + OFF_X0 + (size_t)b * 5184;

  // load x -> H rows
  for (int u = tid; u < 5184; u += 256) {
    int s = u >> 6, d = u & 63;
    H[s*68 + d] = xg[u];
  }
  __syncthreads();
  // LN1 stats
  if (tid < 81) {
    const float* xr = H + tid*68;
    float sv = 0.f;
    for (int d = 0; d < 64; ++d) sv += xr[d];
    float mean = sv * (1.f/64.f);
    float sq = 0.f;
    for (int d = 0; d < 64; ++d) { float dv = xr[d]-mean; sq += dv*dv; }
    muv[tid] = mean;
    rsd[tid] = rsqrtf(sq*(1.f/64.f) + EPS);
  }
  __syncthreads();
  // H = LN1(x) in place
  for (int u = tid; u < 5184; u += 256) {
    int s = u >> 6, d = u & 63;
    H[s*68+d] = (H[s*68+d] - muv[s])*rsd[s]*ln1g[l*64+d] + ln1b[l*64+d];
  }

  const int c  = tid & 15;   // col within 16-chunk
  const int sg = tid >> 4;   // row group 0..15

  // head pairs
  for (int p = 0; p < 2; ++p) {
    float* QB = p ? P1 : P0;
    float* KB = p ? P2 : P1;
    float* VB = p ? P3 : P2;
    for (int m = 0; m < 3; ++m) {
      const float* src = (m==0)? wq : (m==1)? wk : wv;
      float* dst = (m==0)? QB : (m==1)? KB : VB;
      for (int h2 = 0; h2 < 2; ++h2) {
        __syncthreads();
        const float* wbase = src + (size_t)(l*4 + 2*p + h2)*1024;
        for (int u = tid; u < 1024; u += 256) Wst[u] = wbase[u];
        __syncthreads();
        float acc[6] = {0.f,0.f,0.f,0.f,0.f,0.f};
        for (int d4 = 0; d4 < 16; ++d4) {
          float w0 = Wst[(d4*4+0)*16 + c];
          float w1 = Wst[(d4*4+1)*16 + c];
          float w2 = Wst[(d4*4+2)*16 + c];
          float w3 = Wst[(d4*4+3)*16 + c];
#pragma unroll
          for (int j = 0; j < 6; ++j) {
            int s = sg + 16*j;
            if (s < 81) {
              const float4 xv = *(const float4*)(H + s*68 + d4*4);
              acc[j] = fmaf(xv.x, w0, acc[j]);
              acc[j] = fmaf(xv.y, w1, acc[j]);
              acc[j] = fmaf(xv.z, w2, acc[j]);
              acc[j] = fmaf(xv.w, w3, acc[j]);
            }
          }
        }
#pragma unroll
        for (int j = 0; j < 6; ++j) {
          int s = sg + 16*j;
          if (s < 81) dst[s*33 + h2*16 + c] = acc[j];
        }
      }
    }
    __syncthreads();
    // rotary on QB (*xs) and KB (/xs), both heads of the pair
    for (int u = tid; u < 2592; u += 256) {
      int m = u / 1296;
      int rem = u - m*1296;
      int h2 = rem / 648;
      int r = rem - h2*648;
      int pp = r & 7, s = r >> 3;
      float scale = (2.f*pp + 6.4f) / 22.4f;
      float xs = powf(scale, (float)s / 512.f);
      float invf = powf(10000.f, -(float)pp / 8.f);
      float ang = (float)s * invf;
      float cx = cosf(ang), sn = sinf(ang);
      float cu, su;
      if (m == 0) { cu = cx*xs; su = sn*xs; }
      else        { cu = cx/xs; su = sn/xs; }
      float* ptr = (m ? KB : QB) + s*33 + h2*16 + 2*pp;
      float a = ptr[0], bb2 = ptr[1];
      ptr[0] = a*cu - bb2*su;
      ptr[1] = bb2*cu + a*su;
    }
    __syncthreads();
    // retention + groupnorm -> gn written into this thread's OWN q slot (safe)
    if (tid < 162) {
      int h2 = tid & 1, s = tid >> 1;
      int hd = 2*p + h2;
      float g = 1.f - expf(-3.4657359f + (float)hd * (-0.92419624f));
      float lg = log2f(g);
      float q[16];
#pragma unroll
      for (int k = 0; k < 16; ++k) q[k] = QB[s*33 + h2*16 + k];
      float yh[16];
#pragma unroll
      for (int v = 0; v < 16; ++v) yh[v] = 0.f;
      for (int tt = 0; tt <= s; ++tt) {
        const float* Kr = KB + tt*33 + h2*16;
        float a = 0.f;
#pragma unroll
        for (int k = 0; k < 16; ++k) a = fmaf(q[k], Kr[k], a);
        a *= exp2f((float)(s - tt) * lg);
        const float* Vr = VB + tt*33 + h2*16;
#pragma unroll
        for (int v = 0; v < 16; ++v) yh[v] = fmaf(a, Vr[v], yh[v]);
      }
      float sv = 0.f;
#pragma unroll
      for (int v = 0; v < 16; ++v) sv += yh[v];
      float mean = sv * (1.f/16.f);
      float sq = 0.f;
#pragma unroll
      for (int v = 0; v < 16; ++v) { float dv = yh[v]-mean; sq += dv*dv; }
      float rstd = rsqrtf(sq*(1.f/16.f) + EPS);
#pragma unroll
      for (int v = 0; v < 16; ++v) {
        int col = hd*16 + v;
        QB[s*33 + h2*16 + v] = (yh[v]-mean)*rstd*gng[l*64+col] + gnb[l*64+col];
      }
    }
  }

  // gate: G = H @ wg into registers (24 values/thread)
  float Gr[4][6];
#pragma unroll
  for (int cc = 0; cc < 4; ++cc) {
    __syncthreads();
    for (int u = tid; u < 1024; u += 256)
      Wst[u] = wgp[(l*64 + (u>>4))*64 + cc*16 + (u&15)];
    __syncthreads();
#pragma unroll
    for (int j = 0; j < 6; ++j) Gr[cc][j] = 0.f;
    for (int d4 = 0; d4 < 16; ++d4) {
      float w0 = Wst[(d4*4+0)*16 + c];
      float w1 = Wst[(d4*4+1)*16 + c];
      float w2 = Wst[(d4*4+2)*16 + c];
      float w3 = Wst[(d4*4+3)*16 + c];
#pragma unroll
      for (int j = 0; j < 6; ++j) {
        int s = sg + 16*j;
        if (s < 81) {
          const float4 xv = *(const float4*)(H + s*68 + d4*4);
          Gr[cc][j] = fmaf(xv.x, w0, Gr[cc][j]);
          Gr[cc][j] = fmaf(xv.y, w1, Gr[cc][j]);
          Gr[cc][j] = fmaf(xv.z, w2, Gr[cc][j]);
          Gr[cc][j] = fmaf(xv.w, w3, Gr[cc][j]);
        }
      }
    }
  }
  __syncthreads();
  // overwrite H with Z = silu(G) * Yc   (col = cc*16+c -> head cc)
#pragma unroll
  for (int cc = 0; cc < 4; ++cc) {
#pragma unroll
    for (int j = 0; j < 6; ++j) {
      int s = sg + 16*j;
      if (s < 81) {
        float gn = (cc < 2 ? P0 : P1)[s*33 + (cc&1)*16 + c];
        float g = Gr[cc][j];
        float sig = 1.f/(1.f+expf(-g));
        H[s*68 + cc*16 + c] = g*sig*gn;
      }
    }
  }

  // wo: y = Z @ wo + x -> global OFF_Y
  float* yg = ws + OFF_Y + (size_t)b * 5184;
  for (int cc = 0; cc < 4; ++cc) {
    __syncthreads();
    for (int u = tid; u < 1024; u += 256)
      Wst[u] = wop[(l*64 + (u>>4))*64 + cc*16 + (u&15)];
    __syncthreads();
    float acc[6] = {0.f,0.f,0.f,0.f,0.f,0.f};
    for (int d4 = 0; d4 < 16; ++d4) {
      float w0 = Wst[(d4*4+0)*16 + c];
      float w1 = Wst[(d4*4+1)*16 + c];
      float w2 = Wst[(d4*4+2)*16 + c];
      float w3 = Wst[(d4*4+3)*16 + c];
#pragma unroll
      for (int j = 0; j < 6; ++j) {
        int s = sg + 16*j;
        if (s < 81) {
          const float4 xv = *(const float4*)(H + s*68 + d4*4);
          acc[j] = fmaf(xv.x, w0, acc[j]);
          acc[j] = fmaf(xv.y, w1, acc[j]);
          acc[j] = fmaf(xv.z, w2, acc[j]);
          acc[j] = fmaf(xv.w, w3, acc[j]);
        }
      }
    }
#pragma unroll
    for (int j = 0; j < 6; ++j) {
      int s = sg + 16*j;
      if (s < 81) {
        int u = s*64 + cc*16 + c;
        yg[u] = acc[j] + xg[u];
      }
    }
  }
}

// ---------------- ff_layer v3: two-half F1, 48.8 KB LDS (3 blocks/CU) ----------------
__global__ __launch_bounds__(256) void ff_layer(const float* ws_in, float* ws,
    const float* fw1, const float* fb1, const float* fw2, const float* fb2,
    const float* ln2g, const float* ln2b, int l)
{
  __shared__ __align__(16) float H2[81*68];
  __shared__ __align__(16) float F1h[81*68];   // one 64-col half of F1
  __shared__ float Wst[1024];
  __shared__ float muv[81], rsd[81];
  const int tid = threadIdx.x;
  const int b = blockIdx.x;
  const float* yg = ws_in + OFF_Y + (size_t)b * 5184;

  for (int u = tid; u < 5184; u += 256) {
    int s = u >> 6, d = u & 63;
    H2[s*68 + d] = yg[u];
  }
  __syncthreads();
  if (tid < 81) {
    const float* xr = H2 + tid*68;
    float sv = 0.f;
    for (int d = 0; d < 64; ++d) sv += xr[d];
    float mean = sv * (1.f/64.f);
    float sq = 0.f;
    for (int d = 0; d < 64; ++d) { float dv = xr[d]-mean; sq += dv*dv; }
    muv[tid] = mean;
    rsd[tid] = rsqrtf(sq*(1.f/64.f) + EPS);
  }
  __syncthreads();
  for (int u = tid; u < 5184; u += 256) {
    int s = u >> 6, d = u & 63;
    H2[s*68+d] = (H2[s*68+d] - muv[s])*rsd[s]*ln2g[l*64+d] + ln2b[l*64+d];
  }

  const int c   = tid & 15;
  const int sg  = tid >> 4;
  const int c2  = tid & 63;
  const int sg2 = tid >> 6;
  float acc2[21];
#pragma unroll
  for (int i = 0; i < 21; ++i) acc2[i] = 0.f;

  for (int qq = 0; qq < 2; ++qq) {
    // ffn1 half: F1h = gelu(H2 @ fw1[:, qq*64 .. qq*64+63] + fb1)
    for (int fc = 0; fc < 4; ++fc) {
      __syncthreads();
      for (int u = tid; u < 1024; u += 256)
        Wst[u] = fw1[(l*64 + (u>>4))*128 + qq*64 + fc*16 + (u&15)];
      __syncthreads();
      float acc[6] = {0.f,0.f,0.f,0.f,0.f,0.f};
      for (int d4 = 0; d4 < 16; ++d4) {
        float w0 = Wst[(d4*4+0)*16 + c];
        float w1 = Wst[(d4*4+1)*16 + c];
        float w2 = Wst[(d4*4+2)*16 + c];
        float w3 = Wst[(d4*4+3)*16 + c];
#pragma unroll
        for (int j = 0; j < 6; ++j) {
          int s = sg + 16*j;
          if (s < 81) {
            const float4 xv = *(const float4*)(H2 + s*68 + d4*4);
            acc[j] = fmaf(xv.x, w0, acc[j]);
            acc[j] = fmaf(xv.y, w1, acc[j]);
            acc[j] = fmaf(xv.z, w2, acc[j]);
            acc[j] = fmaf(xv.w, w3, acc[j]);
          }
        }
      }
#pragma unroll
      for (int j = 0; j < 6; ++j) {
        int s = sg + 16*j;
        if (s < 81) {
          float pp = acc[j] + fb1[l*128 + qq*64 + fc*16 + c];
          F1h[s*68 + fc*16 + c] = 0.5f*pp*(1.f + erff(pp*0.70710678118f));
        }
      }
    }
    // ffn2 half accumulate
    for (int fc = 0; fc < 4; ++fc) {
      __syncthreads();
      for (int u = tid; u < 1024; u += 256)
        Wst[u] = fw2[(l*128 + qq*64 + fc*16 + (u>>6))*64 + (u&63)];
      __syncthreads();
      float w[16];
#pragma unroll
      for (int f = 0; f < 16; ++f) w[f] = Wst[f*64 + c2];
#pragma unroll
      for (int i = 0; i < 21; ++i) {
        int s = sg2 + 4*i;
        if (s < 81) {
          const float4* fr = (const float4*)(F1h + s*68 + fc*16);
          float4 f0 = fr[0], f1 = fr[1], f2 = fr[2], f3 = fr[3];
          float a = acc2[i];
          a = fmaf(f0.x, w[0],  a); a = fmaf(f0.y, w[1],  a);
          a = fmaf(f0.z, w[2],  a); a = fmaf(f0.w, w[3],  a);
          a = fmaf(f1.x, w[4],  a); a = fmaf(f1.y, w[5],  a);
          a = fmaf(f1.z, w[6],  a); a = fmaf(f1.w, w[7],  a);
          a = fmaf(f2.x, w[8],  a); a = fmaf(f2.y, w[9],  a);
          a = fmaf(f2.z, w[10], a); a = fmaf(f2.w, w[11], a);
          a = fmaf(f3.x, w[12], a); a = fmaf(f3.y, w[13], a);
          a = fmaf(f3.z, w[14], a); a = fmaf(f3.w, w[15], a);
          acc2[i] = a;
        }
      }
    }
  }
  float* xg = ws + OFF_X0 + (size_t)b * 5184;
#pragma unroll
  for (int i = 0; i < 21; ++i) {
    int s = sg2 + 4*i;
    if (s < 81) {
      int u = s*64 + c2;
      xg[u] = acc2[i] + fb2[l*64 + c2] + yg[u];
    }
  }
}

// ---------------- fcls: classifier, one block per batch ----------------
__global__ __launch_bounds__(256) void fcls(const float* ws_in, const float* nn1w,
                                            const float* nn1b, float* out) {
  __shared__ float red[256];
  const int tid = threadIdx.x;
  const int b = blockIdx.x;
  const float* Xr = ws_in + OFF_X0 + (size_t)b * 5184;
  int c = tid & 15, chunk = tid >> 4;
  int i0 = chunk * 324;
  float a = 0.f;
  for (int i = 0; i < 324; ++i)
    a = fmaf(Xr[i0+i], nn1w[(size_t)(i0+i)*16 + c], a);
  red[tid] = a;
  __syncthreads();
  if (tid < 16) {
    float s = nn1b[tid];
#pragma unroll
    for (int j = 0; j < 16; ++j) s += red[j*16 + tid];
    out[b*16 + tid] = s;
  }
}

// ---------------- launch ----------------
extern "C" void kernel_launch(void* const* d_in, const int* in_sizes, int n_in,
                              void* d_out, int out_size, void* d_ws, size_t ws_size,
                              hipStream_t stream) {
  const float* X    = (const float*)d_in[0];
  const float* c3w  = (const float*)d_in[1];
  const float* c3b  = (const float*)d_in[2];
  const float* bn3g = (const float*)d_in[3];
  const float* bn3b = (const float*)d_in[4];
  const float* c2w  = (const float*)d_in[5];
  const float* c2b  = (const float*)d_in[6];
  const float* bn2g = (const float*)d_in[7];
  const float* bn2b = (const float*)d_in[8];
  const float* wq   = (const float*)d_in[9];
  const float* wk   = (const float*)d_in[10];
  const float* wv   = (const float*)d_in[11];
  const float* wg   = (const float*)d_in[12];
  const float* wo   = (const float*)d_in[13];
  const float* gng  = (const float*)d_in[14];
  const float* gnb  = (const float*)d_in[15];
  const float* ln1g = (const float*)d_in[16];
  const float* ln1b = (const float*)d_in[17];
  const float* ln2g = (const float*)d_in[18];
  const float* ln2b = (const float*)d_in[19];
  const float* fw1  = (const float*)d_in[20];
  const float* fb1  = (const float*)d_in[21];
  const float* fw2  = (const float*)d_in[22];
  const float* fb2  = (const float*)d_in[23];
  const float* nn1w = (const float*)d_in[24];
  const float* nn1b = (const float*)d_in[25];
  float* ws = (float*)d_ws;
  float* out = (float*)d_out;

  // conv stage
  kd1_conv1<<<108416, 256, 0, stream>>>(X, c3w, c3b, ws);
  kd2_bn1part<<<8192, 256, 0, stream>>>(ws, ws);
  kd3_bn1fin<<<1, 64, 0, stream>>>(ws, bn3g, bn3b);
  kd5_conv2<<<dim3(1024, 2), 192, 0, stream>>>(ws, c2w, ws);
  kd6_bn2part<<<1024, 64, 0, stream>>>(ws, ws, c2b);
  kd7_bn2fin<<<1, 64, 0, stream>>>(ws, bn2g, bn2b);
  kd8_tokens<<<20736, 256, 0, stream>>>(ws);

  // transformer layers (fused per-batch)
  for (int l = 0; l < 2; ++l) {
    fa_layer<<<1024, 256, 0, stream>>>(ws, ws, wq, wk, wv, wg, wo,
                                       ln1g, ln1b, gng, gnb, l);
    ff_layer<<<1024, 256, 0, stream>>>(ws, ws, fw1, fb1, fw2, fb2,
                                       ln2g, ln2b, l);
  }

  fcls<<<1024, 256, 0, stream>>>(ws, nn1w, nn1b, out);
}

// Round 9
// 1932.508 us; speedup vs baseline: 1.4576x; 1.4576x over previous
//
#include <hip/hip_runtime.h>
#include <math.h>

#define EPS 1e-5f

// ---------------- float offsets in ws ----------------
#define OFF_A  0u          // conv1 out [1024][8][28][11][11] = 27,754,496 (dead after conv2)
#define OFF_X0 0u          // tokens x  [1024][81][64] = 5,308,416 (written after A dead)
#define OFF_Y  31850496u   // y [1024][81][64]; conv2 partial A during conv stage
#define OFF_PA 31850496u   // conv2 partial (ci 0..111)   -- dead before fa writes OFF_Y
#define OFF_PB 37158912u   // conv2 partial (ci 112..223)
#define OFF_B  47775744u   // conv2 out [1024][64][81] = 5,308,416
#define OFF_P  53084160u   // partials  131,072
#define OFF_ST 53215232u   // scale1[8] shift1[8] scale2[64] shift2[64]

// ---------------- kd1: conv3d + bias -> A ----------------
__global__ __launch_bounds__(256) void kd1_conv1(const float* X, const float* c3w,
                                                 const float* c3b, float* ws) {
  int idx = blockIdx.x * 256 + threadIdx.x;
  if (idx >= 27754496) return;
  int pos = idx;
  int w = pos % 11; pos /= 11;
  int h = pos % 11; pos /= 11;
  int dd = pos % 28; pos /= 28;
  int o1 = pos % 8;
  int b = pos / 8;
  const float* Xb = X + (size_t)b * 5070;
  float a = c3b[o1];
#pragma unroll
  for (int kd = 0; kd < 3; ++kd)
#pragma unroll
    for (int kh = 0; kh < 3; ++kh)
#pragma unroll
      for (int kw = 0; kw < 3; ++kw)
        a = fmaf(Xb[(dd+kd)*169 + (h+kh)*13 + (w+kw)],
                 c3w[o1*27 + kd*9 + kh*3 + kw], a);
  ws[OFF_A + idx] = a;
}

// ---------------- kd2: BN1 partial sums per (b, o1) ----------------
__global__ __launch_bounds__(256) void kd2_bn1part(const float* ws_in, float* ws) {
  __shared__ float sS[256], sQ[256];
  int blk = blockIdx.x;               // b*8 + o1
  int tid = threadIdx.x;
  const float* Ab = ws_in + OFF_A + (size_t)blk * 3388;
  float S = 0.f, Q = 0.f;
  for (int i = tid; i < 3388; i += 256) {
    float v = Ab[i];
    S += v; Q += v * v;
  }
  sS[tid] = S; sQ[tid] = Q;
  __syncthreads();
  for (int st = 128; st > 0; st >>= 1) {
    if (tid < st) { sS[tid] += sS[tid+st]; sQ[tid] += sQ[tid+st]; }
    __syncthreads();
  }
  if (tid == 0) {
    ws[OFF_P + blk*2]     = sS[0];
    ws[OFF_P + blk*2 + 1] = sQ[0];
  }
}

// ---------------- kd3: BN1 finalize ----------------
__global__ void kd3_bn1fin(float* ws, const float* bn3g, const float* bn3b) {
  int t = threadIdx.x;
  if (t < 8) {
    float S = 0.f, Q = 0.f;
    for (int j = t; j < 8192; j += 8) {
      S += ws[OFF_P + j*2];
      Q += ws[OFF_P + j*2 + 1];
    }
    float n = 3469312.f;
    float mean = S / n;
    float var = Q / n - mean * mean;
    float sc = bn3g[t] * rsqrtf(var + EPS);
    ws[OFF_ST + t]     = sc;
    ws[OFF_ST + 8 + t] = bn3b[t] - mean * sc;
  }
}

// ---------------- kd5: conv2 split-K, per-(batch,half) LDS-tiled ----------------
__global__ __launch_bounds__(192) void kd5_conv2(const float* ws_in, const float* c2w,
                                                 float* ws) {
  __shared__ float wl[4752];    // [kk 9][ciL 8][oc pad 66]
  __shared__ float inl[1056];   // [ciL 8][11 rows x 12]
  __shared__ float bn1[16];
  int tid = threadIdx.x;
  int b = blockIdx.x;
  int half = blockIdx.y;        // 0: ci 0..111, 1: ci 112..223
  int o = tid / 3, q = tid - o*3;
  if (tid < 16) bn1[tid] = ws_in[OFF_ST + tid];
  const float* Ab = ws_in + OFF_A + (size_t)b * 27104;   // [224][11][11]
  float acc[3][9];
#pragma unroll
  for (int ir = 0; ir < 3; ++ir)
#pragma unroll
    for (int x = 0; x < 9; ++x) acc[ir][x] = 0.f;

  for (int c14 = 0; c14 < 14; ++c14) {
    int cc = half*14 + c14;
    __syncthreads();
#pragma unroll
    for (int it = 0; it < 24; ++it) {
      int j = tid + 192*it;
      int og = j / 72, r = j - og*72;
      int ciL = r / 9, kk = r - ciL*9;
      wl[kk*528 + ciL*66 + og] = c2w[(og*224 + cc*8 + ciL)*9 + kk];
    }
#pragma unroll
    for (int it = 0; it < 6; ++it) {
      int e = tid + 192*it;
      if (e < 968) {
        int ciL = e / 121, pos = e - ciL*121;
        int h = pos / 11, w = pos - h*11;
        int ci = cc*8 + ciL;
        int o1 = ci / 28;
        float raw = Ab[(size_t)ci*121 + pos];
        float v = bn1[o1]*raw + bn1[8+o1];
        inl[ciL*132 + h*12 + w] = fmaxf(v, 0.f);
      }
    }
    __syncthreads();
    for (int ciL = 0; ciL < 8; ++ciL) {
      float rr[5][12];
#pragma unroll
      for (int r5 = 0; r5 < 5; ++r5) {
        const float4* rp = (const float4*)(inl + ciL*132 + (q*3 + r5)*12);
        float4 A4 = rp[0], B4 = rp[1], C4 = rp[2];
        rr[r5][0]=A4.x; rr[r5][1]=A4.y; rr[r5][2]=A4.z; rr[r5][3]=A4.w;
        rr[r5][4]=B4.x; rr[r5][5]=B4.y; rr[r5][6]=B4.z; rr[r5][7]=B4.w;
        rr[r5][8]=C4.x; rr[r5][9]=C4.y; rr[r5][10]=C4.z; rr[r5][11]=C4.w;
      }
#pragma unroll
      for (int ki = 0; ki < 3; ++ki) {
#pragma unroll
        for (int kj = 0; kj < 3; ++kj) {
          float wv = wl[(ki*3+kj)*528 + ciL*66 + o];
#pragma unroll
          for (int ir = 0; ir < 3; ++ir)
#pragma unroll
            for (int x = 0; x < 9; ++x)
              acc[ir][x] = fmaf(rr[ir+ki][x+kj], wv, acc[ir][x]);
        }
      }
    }
  }
  float* dst = ws + (half ? OFF_PB : OFF_PA) + ((size_t)b*64 + o)*81;
#pragma unroll
  for (int ir = 0; ir < 3; ++ir)
#pragma unroll
    for (int x = 0; x < 9; ++x)
      dst[(q*3+ir)*9 + x] = acc[ir][x];
}

// ---------------- kd6: merge conv2 halves + bias -> B; BN2 partials ----------------
__global__ void kd6_bn2part(const float* ws_in, float* ws, const float* c2b) {
  int b = blockIdx.x, t = threadIdx.x;  // t = channel (64 threads)
  const float* pa = ws_in + OFF_PA + (size_t)b * 5184 + t * 81;
  const float* pb = ws_in + OFF_PB + (size_t)b * 5184 + t * 81;
  float* Bb = ws + OFF_B + (size_t)b * 5184 + t * 81;
  float bias = c2b[t];
  float S = 0.f, Q = 0.f;
  for (int s = 0; s < 81; ++s) {
    float v = pa[s] + pb[s] + bias;
    Bb[s] = v;
    S += v; Q += v * v;
  }
  ws[OFF_P + b*128 + t]      = S;
  ws[OFF_P + b*128 + 64 + t] = Q;
}

// ---------------- kd7: BN2 finalize ----------------
__global__ void kd7_bn2fin(float* ws, const float* bn2g, const float* bn2b) {
  int t = threadIdx.x;
  float S = 0.f, Q = 0.f;
  for (int b = 0; b < 1024; ++b) {
    S += ws[OFF_P + b*128 + t];
    Q += ws[OFF_P + b*128 + 64 + t];
  }
  float n = 82944.f;
  float mean = S / n;
  float var = Q / n - mean * mean;
  float sc = bn2g[t] * rsqrtf(var + EPS);
  ws[OFF_ST + 16 + t] = sc;
  ws[OFF_ST + 80 + t] = bn2b[t] - mean * sc;
}

// ---------------- kd8: BN2 apply + relu + transpose -> X0 [b][s][64] ----------------
__global__ __launch_bounds__(256) void kd8_tokens(float* ws) {
  int idx = blockIdx.x * 256 + threadIdx.x;
  if (idx >= 5308416) return;
  int o = idx % 64;
  int s = (idx / 64) % 81;
  int b = idx / 5184;
  float v = ws[OFF_ST + 16 + o] * ws[OFF_B + (size_t)b*5184 + o*81 + s] + ws[OFF_ST + 80 + o];
  ws[OFF_X0 + idx] = fmaxf(v, 0.f);
}

// ---------------- fa_layer v4: phase-local registers only; Z overlays dead P2||P3 ----------------
// sm layout (floats): H[81*68]=5508 | P0[81*34] | P1 | P2 | P3 | Wst[1024] | muv[81] | rsd[81]
// Z = [81][68] over P2..P3 (exactly 2*2754 = 5508), valid only after pair-1 retention.
__global__ __launch_bounds__(256) void fa_layer(const float* ws_in, float* ws,
    const float* wq, const float* wk, const float* wv, const float* wgp, const float* wop,
    const float* ln1g, const float* ln1b, const float* gng, const float* gnb, int l)
{
  __shared__ __align__(16) float sm[17710];
  float* H   = sm;            // [81][68]
  float* P0  = sm + 5508;     // [81][34]
  float* P1  = sm + 8262;
  float* P2  = sm + 11016;
  float* P3  = sm + 13770;
  float* Zb  = sm + 11016;    // [81][68] overlay of P2||P3
  float* Wst = sm + 16524;    // [64][16]
  float* muv = sm + 17548;
  float* rsd = sm + 17629;
  const int tid = threadIdx.x;
  const int b = blockIdx.x;
  const float* xg = ws_in + OFF_X0 + (size_t)b * 5184;

  // load x -> H rows
  for (int u = tid; u < 5184; u += 256) {
    int s = u >> 6, d = u & 63;
    H[s*68 + d] = xg[u];
  }
  __syncthreads();
  // LN1 stats
  if (tid < 81) {
    const float* xr = H + tid*68;
    float sv = 0.f;
    for (int d = 0; d < 64; ++d) sv += xr[d];
    float mean = sv * (1.f/64.f);
    float sq = 0.f;
    for (int d = 0; d < 64; ++d) { float dv = xr[d]-mean; sq += dv*dv; }
    muv[tid] = mean;
    rsd[tid] = rsqrtf(sq*(1.f/64.f) + EPS);
  }
  __syncthreads();
  // H = LN1(x) in place
  for (int u = tid; u < 5184; u += 256) {
    int s = u >> 6, d = u & 63;
    H[s*68+d] = (H[s*68+d] - muv[s])*rsd[s]*ln1g[l*64+d] + ln1b[l*64+d];
  }

  const int c  = tid & 15;   // col within 16-chunk
  const int sg = tid >> 4;   // row group 0..15

  // head pairs
  for (int p = 0; p < 2; ++p) {
    float* QB = p ? P1 : P0;
    float* KB = p ? P2 : P1;
    float* VB = p ? P3 : P2;
    for (int m = 0; m < 3; ++m) {
      const float* src = (m==0)? wq : (m==1)? wk : wv;
      float* dst = (m==0)? QB : (m==1)? KB : VB;
      for (int h2 = 0; h2 < 2; ++h2) {
        __syncthreads();
        const float* wbase = src + (size_t)(l*4 + 2*p + h2)*1024;
        for (int u = tid; u < 1024; u += 256) Wst[u] = wbase[u];
        __syncthreads();
        float acc[6] = {0.f,0.f,0.f,0.f,0.f,0.f};
        for (int d4 = 0; d4 < 16; ++d4) {
          float w0 = Wst[(d4*4+0)*16 + c];
          float w1 = Wst[(d4*4+1)*16 + c];
          float w2 = Wst[(d4*4+2)*16 + c];
          float w3 = Wst[(d4*4+3)*16 + c];
#pragma unroll
          for (int j = 0; j < 6; ++j) {
            int s = sg + 16*j;
            if (s < 81) {
              const float4 xv = *(const float4*)(H + s*68 + d4*4);
              acc[j] = fmaf(xv.x, w0, acc[j]);
              acc[j] = fmaf(xv.y, w1, acc[j]);
              acc[j] = fmaf(xv.z, w2, acc[j]);
              acc[j] = fmaf(xv.w, w3, acc[j]);
            }
          }
        }
#pragma unroll
        for (int j = 0; j < 6; ++j) {
          int s = sg + 16*j;
          if (s < 81) dst[s*34 + h2*16 + c] = acc[j];
        }
      }
    }
    __syncthreads();
    // rotary on QB (*xs) and KB (/xs), both heads of the pair
    for (int u = tid; u < 2592; u += 256) {
      int m = u / 1296;
      int rem = u - m*1296;
      int h2 = rem / 648;
      int r = rem - h2*648;
      int pp = r & 7, s = r >> 3;
      float scale = (2.f*pp + 6.4f) / 22.4f;
      float xs = powf(scale, (float)s / 512.f);
      float invf = powf(10000.f, -(float)pp / 8.f);
      float ang = (float)s * invf;
      float cx = cosf(ang), sn = sinf(ang);
      float cu, su;
      if (m == 0) { cu = cx*xs; su = sn*xs; }
      else        { cu = cx/xs; su = sn/xs; }
      float* ptr = (m ? KB : QB) + s*34 + h2*16 + 2*pp;
      float a = ptr[0], bb2 = ptr[1];
      ptr[0] = a*cu - bb2*su;
      ptr[1] = bb2*cu + a*su;
    }
    __syncthreads();
    // retention + groupnorm -> gn into this thread's OWN q slot
    if (tid < 162) {
      int h2 = tid & 1, s = tid >> 1;
      int hd = 2*p + h2;
      float g = 1.f - expf(-3.4657359f + (float)hd * (-0.92419624f));
      float lg = log2f(g);
      float q[16];
#pragma unroll
      for (int k = 0; k < 16; ++k) q[k] = QB[s*34 + h2*16 + k];
      float yh[16];
#pragma unroll
      for (int v = 0; v < 16; ++v) yh[v] = 0.f;
      for (int tt = 0; tt <= s; ++tt) {
        const float* Kr = KB + tt*34 + h2*16;
        float a = 0.f;
#pragma unroll
        for (int k = 0; k < 16; ++k) a = fmaf(q[k], Kr[k], a);
        a *= exp2f((float)(s - tt) * lg);
        const float* Vr = VB + tt*34 + h2*16;
#pragma unroll
        for (int v = 0; v < 16; ++v) yh[v] = fmaf(a, Vr[v], yh[v]);
      }
      float sv = 0.f;
#pragma unroll
      for (int v = 0; v < 16; ++v) sv += yh[v];
      float mean = sv * (1.f/16.f);
      float sq = 0.f;
#pragma unroll
      for (int v = 0; v < 16; ++v) { float dv = yh[v]-mean; sq += dv*dv; }
      float rstd = rsqrtf(sq*(1.f/16.f) + EPS);
#pragma unroll
      for (int v = 0; v < 16; ++v) {
        int col = hd*16 + v;
        QB[s*34 + h2*16 + v] = (yh[v]-mean)*rstd*gng[l*64+col] + gnb[l*64+col];
      }
    }
  }
  // here: P0 = gn heads 0,1; P1 = gn heads 2,3; P2/P3 dead -> Z region

  // gate: per chunk, Z[:, cc*16+c] = silu(G) * gn   (phase-local registers only)
  for (int cc = 0; cc < 4; ++cc) {
    __syncthreads();
    for (int u = tid; u < 1024; u += 256)
      Wst[u] = wgp[(l*64 + (u>>4))*64 + cc*16 + (u&15)];
    __syncthreads();
    float acc[6] = {0.f,0.f,0.f,0.f,0.f,0.f};
    for (int d4 = 0; d4 < 16; ++d4) {
      float w0 = Wst[(d4*4+0)*16 + c];
      float w1 = Wst[(d4*4+1)*16 + c];
      float w2 = Wst[(d4*4+2)*16 + c];
      float w3 = Wst[(d4*4+3)*16 + c];
#pragma unroll
      for (int j = 0; j < 6; ++j) {
        int s = sg + 16*j;
        if (s < 81) {
          const float4 xv = *(const float4*)(H + s*68 + d4*4);
          acc[j] = fmaf(xv.x, w0, acc[j]);
          acc[j] = fmaf(xv.y, w1, acc[j]);
          acc[j] = fmaf(xv.z, w2, acc[j]);
          acc[j] = fmaf(xv.w, w3, acc[j]);
        }
      }
    }
    const float* gnb_ = (cc < 2 ? P0 : P1);
#pragma unroll
    for (int j = 0; j < 6; ++j) {
      int s = sg + 16*j;
      if (s < 81) {
        float gn = gnb_[s*34 + (cc&1)*16 + c];
        float g = acc[j];
        float sig = 1.f/(1.f+expf(-g));
        Zb[s*68 + cc*16 + c] = g*sig*gn;
      }
    }
  }

  // wo: y = Z @ wo + x -> global OFF_Y
  float* yg = ws + OFF_Y + (size_t)b * 5184;
  for (int cc = 0; cc < 4; ++cc) {
    __syncthreads();
    for (int u = tid; u < 1024; u += 256)
      Wst[u] = wop[(l*64 + (u>>4))*64 + cc*16 + (u&15)];
    __syncthreads();
    float acc[6] = {0.f,0.f,0.f,0.f,0.f,0.f};
    for (int d4 = 0; d4 < 16; ++d4) {
      float w0 = Wst[(d4*4+0)*16 + c];
      float w1 = Wst[(d4*4+1)*16 + c];
      float w2 = Wst[(d4*4+2)*16 + c];
      float w3 = Wst[(d4*4+3)*16 + c];
#pragma unroll
      for (int j = 0; j < 6; ++j) {
        int s = sg + 16*j;
        if (s < 81) {
          const float4 xv = *(const float4*)(Zb + s*68 + d4*4);
          acc[j] = fmaf(xv.x, w0, acc[j]);
          acc[j] = fmaf(xv.y, w1, acc[j]);
          acc[j] = fmaf(xv.z, w2, acc[j]);
          acc[j] = fmaf(xv.w, w3, acc[j]);
        }
      }
    }
#pragma unroll
    for (int j = 0; j < 6; ++j) {
      int s = sg + 16*j;
      if (s < 81) {
        int u = s*64 + cc*16 + c;
        yg[u] = acc[j] + xg[u];
      }
    }
  }
}

// ---------------- ff_layer v3: two-half F1, 48.8 KB LDS ----------------
__global__ __launch_bounds__(256) void ff_layer(const float* ws_in, float* ws,
    const float* fw1, const float* fb1, const float* fw2, const float* fb2,
    const float* ln2g, const float* ln2b, int l)
{
  __shared__ __align__(16) float H2[81*68];
  __shared__ __align__(16) float F1h[81*68];   // one 64-col half of F1
  __shared__ float Wst[1024];
  __shared__ float muv[81], rsd[81];
  const int tid = threadIdx.x;
  const int b = blockIdx.x;
  const float* yg = ws_in + OFF_Y + (size_t)b * 5184;

  for (int u = tid; u < 5184; u += 256) {
    int s = u >> 6, d = u & 63;
    H2[s*68 + d] = yg[u];
  }
  __syncthreads();
  if (tid < 81) {
    const float* xr = H2 + tid*68;
    float sv = 0.f;
    for (int d = 0; d < 64; ++d) sv += xr[d];
    float mean = sv * (1.f/64.f);
    float sq = 0.f;
    for (int d = 0; d < 64; ++d) { float dv = xr[d]-mean; sq += dv*dv; }
    muv[tid] = mean;
    rsd[tid] = rsqrtf(sq*(1.f/64.f) + EPS);
  }
  __syncthreads();
  for (int u = tid; u < 5184; u += 256) {
    int s = u >> 6, d = u & 63;
    H2[s*68+d] = (H2[s*68+d] - muv[s])*rsd[s]*ln2g[l*64+d] + ln2b[l*64+d];
  }

  const int c   = tid & 15;
  const int sg  = tid >> 4;
  const int c2  = tid & 63;
  const int sg2 = tid >> 6;
  float acc2[21];
#pragma unroll
  for (int i = 0; i < 21; ++i) acc2[i] = 0.f;

  for (int qq = 0; qq < 2; ++qq) {
    // ffn1 half: F1h = gelu(H2 @ fw1[:, qq*64 .. qq*64+63] + fb1)
    for (int fc = 0; fc < 4; ++fc) {
      __syncthreads();
      for (int u = tid; u < 1024; u += 256)
        Wst[u] = fw1[(l*64 + (u>>4))*128 + qq*64 + fc*16 + (u&15)];
      __syncthreads();
      float acc[6] = {0.f,0.f,0.f,0.f,0.f,0.f};
      for (int d4 = 0; d4 < 16; ++d4) {
        float w0 = Wst[(d4*4+0)*16 + c];
        float w1 = Wst[(d4*4+1)*16 + c];
        float w2 = Wst[(d4*4+2)*16 + c];
        float w3 = Wst[(d4*4+3)*16 + c];
#pragma unroll
        for (int j = 0; j < 6; ++j) {
          int s = sg + 16*j;
          if (s < 81) {
            const float4 xv = *(const float4*)(H2 + s*68 + d4*4);
            acc[j] = fmaf(xv.x, w0, acc[j]);
            acc[j] = fmaf(xv.y, w1, acc[j]);
            acc[j] = fmaf(xv.z, w2, acc[j]);
            acc[j] = fmaf(xv.w, w3, acc[j]);
          }
        }
      }
#pragma unroll
      for (int j = 0; j < 6; ++j) {
        int s = sg + 16*j;
        if (s < 81) {
          float pp = acc[j] + fb1[l*128 + qq*64 + fc*16 + c];
          F1h[s*68 + fc*16 + c] = 0.5f*pp*(1.f + erff(pp*0.70710678118f));
        }
      }
    }
    // ffn2 half accumulate
    for (int fc = 0; fc < 4; ++fc) {
      __syncthreads();
      for (int u = tid; u < 1024; u += 256)
        Wst[u] = fw2[(l*128 + qq*64 + fc*16 + (u>>6))*64 + (u&63)];
      __syncthreads();
      float w[16];
#pragma unroll
      for (int f = 0; f < 16; ++f) w[f] = Wst[f*64 + c2];
#pragma unroll
      for (int i = 0; i < 21; ++i) {
        int s = sg2 + 4*i;
        if (s < 81) {
          const float4* fr = (const float4*)(F1h + s*68 + fc*16);
          float4 f0 = fr[0], f1 = fr[1], f2 = fr[2], f3 = fr[3];
          float a = acc2[i];
          a = fmaf(f0.x, w[0],  a); a = fmaf(f0.y, w[1],  a);
          a = fmaf(f0.z, w[2],  a); a = fmaf(f0.w, w[3],  a);
          a = fmaf(f1.x, w[4],  a); a = fmaf(f1.y, w[5],  a);
          a = fmaf(f1.z, w[6],  a); a = fmaf(f1.w, w[7],  a);
          a = fmaf(f2.x, w[8],  a); a = fmaf(f2.y, w[9],  a);
          a = fmaf(f2.z, w[10], a); a = fmaf(f2.w, w[11], a);
          a = fmaf(f3.x, w[12], a); a = fmaf(f3.y, w[13], a);
          a = fmaf(f3.z, w[14], a); a = fmaf(f3.w, w[15], a);
          acc2[i] = a;
        }
      }
    }
  }
  float* xg = ws + OFF_X0 + (size_t)b * 5184;
#pragma unroll
  for (int i = 0; i < 21; ++i) {
    int s = sg2 + 4*i;
    if (s < 81) {
      int u = s*64 + c2;
      xg[u] = acc2[i] + fb2[l*64 + c2] + yg[u];
    }
  }
}

// ---------------- fcls: classifier, one block per batch ----------------
__global__ __launch_bounds__(256) void fcls(const float* ws_in, const float* nn1w,
                                            const float* nn1b, float* out) {
  __shared__ float red[256];
  const int tid = threadIdx.x;
  const int b = blockIdx.x;
  const float* Xr = ws_in + OFF_X0 + (size_t)b * 5184;
  int c = tid & 15, chunk = tid >> 4;
  int i0 = chunk * 324;
  float a = 0.f;
  for (int i = 0; i < 324; ++i)
    a = fmaf(Xr[i0+i], nn1w[(size_t)(i0+i)*16 + c], a);
  red[tid] = a;
  __syncthreads();
  if (tid < 16) {
    float s = nn1b[tid];
#pragma unroll
    for (int j = 0; j < 16; ++j) s += red[j*16 + tid];
    out[b*16 + tid] = s;
  }
}

// ---------------- launch ----------------
extern "C" void kernel_launch(void* const* d_in, const int* in_sizes, int n_in,
                              void* d_out, int out_size, void* d_ws, size_t ws_size,
                              hipStream_t stream) {
  const float* X    = (const float*)d_in[0];
  const float* c3w  = (const float*)d_in[1];
  const float* c3b  = (const float*)d_in[2];
  const float* bn3g = (const float*)d_in[3];
  const float* bn3b = (const float*)d_in[4];
  const float* c2w  = (const float*)d_in[5];
  const float* c2b  = (const float*)d_in[6];
  const float* bn2g = (const float*)d_in[7];
  const float* bn2b = (const float*)d_in[8];
  const float* wq   = (const float*)d_in[9];
  const float* wk   = (const float*)d_in[10];
  const float* wv   = (const float*)d_in[11];
  const float* wg   = (const float*)d_in[12];
  const float* wo   = (const float*)d_in[13];
  const float* gng  = (const float*)d_in[14];
  const float* gnb  = (const float*)d_in[15];
  const float* ln1g = (const float*)d_in[16];
  const float* ln1b = (const float*)d_in[17];
  const float* ln2g = (const float*)d_in[18];
  const float* ln2b = (const float*)d_in[19];
  const float* fw1  = (const float*)d_in[20];
  const float* fb1  = (const float*)d_in[21];
  const float* fw2  = (const float*)d_in[22];
  const float* fb2  = (const float*)d_in[23];
  const float* nn1w = (const float*)d_in[24];
  const float* nn1b = (const float*)d_in[25];
  float* ws = (float*)d_ws;
  float* out = (float*)d_out;

  // conv stage
  kd1_conv1<<<108416, 256, 0, stream>>>(X, c3w, c3b, ws);
  kd2_bn1part<<<8192, 256, 0, stream>>>(ws, ws);
  kd3_bn1fin<<<1, 64, 0, stream>>>(ws, bn3g, bn3b);
  kd5_conv2<<<dim3(1024, 2), 192, 0, stream>>>(ws, c2w, ws);
  kd6_bn2part<<<1024, 64, 0, stream>>>(ws, ws, c2b);
  kd7_bn2fin<<<1, 64, 0, stream>>>(ws, bn2g, bn2b);
  kd8_tokens<<<20736, 256, 0, stream>>>(ws);

  // transformer layers (fused per-batch)
  for (int l = 0; l < 2; ++l) {
    fa_layer<<<1024, 256, 0, stream>>>(ws, ws, wq, wk, wv, wg, wo,
                                       ln1g, ln1b, gng, gnb, l);
    ff_layer<<<1024, 256, 0, stream>>>(ws, ws, fw1, fb1, fw2, fb2,
                                       ln2g, ln2b, l);
  }

  fcls<<<1024, 256, 0, stream>>>(ws, nn1w, nn1b, out);
}

// Round 10
// 1655.388 us; speedup vs baseline: 1.7016x; 1.1674x over previous
//
#include <hip/hip_runtime.h>
#include <math.h>

#define EPS 1e-5f

// ---------------- float offsets in ws ----------------
#define OFF_A  0u          // conv1 out [1024][8][28][11][11] = 27,754,496 (dead after conv2)
#define OFF_X0 0u          // tokens x  [1024][81][64] = 5,308,416 (written after A dead)
#define OFF_Y  31850496u   // y [1024][81][64]
#define OFF_B  47775744u   // conv2 out [1024][64][81] = 5,308,416
#define OFF_P  53084160u   // partials  131,072
#define OFF_ST 53215232u   // scale1[8] shift1[8] scale2[64] shift2[64]

typedef __attribute__((ext_vector_type(8))) short short8;
typedef __attribute__((ext_vector_type(4))) float f32x4;

__device__ inline unsigned short f2bf(float f) {
  unsigned int x = __float_as_uint(f);
  unsigned int r = x + 0x7fffu + ((x >> 16) & 1u);
  return (unsigned short)(r >> 16);
}

// ---------------- kd1: conv3d + bias -> A ----------------
__global__ __launch_bounds__(256) void kd1_conv1(const float* X, const float* c3w,
                                                 const float* c3b, float* ws) {
  int idx = blockIdx.x * 256 + threadIdx.x;
  if (idx >= 27754496) return;
  int pos = idx;
  int w = pos % 11; pos /= 11;
  int h = pos % 11; pos /= 11;
  int dd = pos % 28; pos /= 28;
  int o1 = pos % 8;
  int b = pos / 8;
  const float* Xb = X + (size_t)b * 5070;
  float a = c3b[o1];
#pragma unroll
  for (int kd = 0; kd < 3; ++kd)
#pragma unroll
    for (int kh = 0; kh < 3; ++kh)
#pragma unroll
      for (int kw = 0; kw < 3; ++kw)
        a = fmaf(Xb[(dd+kd)*169 + (h+kh)*13 + (w+kw)],
                 c3w[o1*27 + kd*9 + kh*3 + kw], a);
  ws[OFF_A + idx] = a;
}

// ---------------- kd2: BN1 partial sums per (b, o1) ----------------
__global__ __launch_bounds__(256) void kd2_bn1part(const float* ws_in, float* ws) {
  __shared__ float sS[256], sQ[256];
  int blk = blockIdx.x;               // b*8 + o1
  int tid = threadIdx.x;
  const float* Ab = ws_in + OFF_A + (size_t)blk * 3388;
  float S = 0.f, Q = 0.f;
  for (int i = tid; i < 3388; i += 256) {
    float v = Ab[i];
    S += v; Q += v * v;
  }
  sS[tid] = S; sQ[tid] = Q;
  __syncthreads();
  for (int st = 128; st > 0; st >>= 1) {
    if (tid < st) { sS[tid] += sS[tid+st]; sQ[tid] += sQ[tid+st]; }
    __syncthreads();
  }
  if (tid == 0) {
    ws[OFF_P + blk*2]     = sS[0];
    ws[OFF_P + blk*2 + 1] = sQ[0];
  }
}

// ---------------- kd3: BN1 finalize ----------------
__global__ void kd3_bn1fin(float* ws, const float* bn3g, const float* bn3b) {
  int t = threadIdx.x;
  if (t < 8) {
    float S = 0.f, Q = 0.f;
    for (int j = t; j < 8192; j += 8) {
      S += ws[OFF_P + j*2];
      Q += ws[OFF_P + j*2 + 1];
    }
    float n = 3469312.f;
    float mean = S / n;
    float var = Q / n - mean * mean;
    float sc = bn3g[t] * rsqrtf(var + EPS);
    ws[OFF_ST + t]     = sc;
    ws[OFF_ST + 8 + t] = bn3b[t] - mean * sc;
  }
}

// ---------------- kd5: conv2 as bf16 MFMA GEMM (per-batch) ----------------
// C[s][oc] = sum_k Aim[s][k] * W[k][oc],  k = ci*9 + ki*3 + kj,  K=2016 in 7 chunks of 288.
// MFMA 16x16x32 bf16: A row=lane&15, k=(lane>>4)*8+j; B col=lane&15, same k;
// D col=lane&15, row=(lane>>4)*4+reg.
__global__ __launch_bounds__(256) void kd5_conv2_mfma(const float* ws_in, const float* c2w,
                                                      const float* c2b, float* ws) {
  __shared__ unsigned short AimU[96*296];   // im2col tile, rows padded to 296 (bank decorrelation)
  __shared__ unsigned short InsU[32*124];   // BN1+relu'd conv1 slab chunk, bf16
  __shared__ float bn1[16];
  const int tid  = threadIdx.x;
  const int b    = blockIdx.x;
  const int wid  = tid >> 6;
  const int lane = tid & 63;
  if (tid < 16) bn1[tid] = ws_in[OFF_ST + tid];
  const float* Ab = ws_in + OFF_A + (size_t)b * 27104;   // [224][121]

  const int col = wid*16 + (lane & 15);     // this wave's output column (oc)
  const int kgrp = lane >> 4;               // 0..3
  f32x4 acc[6];
#pragma unroll
  for (int mt = 0; mt < 6; ++mt) acc[mt] = (f32x4){0.f,0.f,0.f,0.f};

  for (int cc = 0; cc < 7; ++cc) {
    __syncthreads();   // previous chunk's MFMA reads complete
    // stage In chunk: 32 ci x 121, BN1+relu, to bf16
    for (int e = tid; e < 3872; e += 256) {
      int ciL = e / 121, pos = e - ciL*121;
      int ci = cc*32 + ciL;
      int o1 = ci / 28;
      float raw = Ab[(size_t)ci*121 + pos];
      float v = fmaxf(bn1[o1]*raw + bn1[8+o1], 0.f);
      InsU[ciL*124 + pos] = f2bf(v);
    }
    __syncthreads();
    // build im2col tile: per element-triple (s, ciL, ki) -> k = ciL*9 + ki*3 + {0,1,2}
    for (int e = tid; e < 9216; e += 256) {
      int s = e / 96;
      int t3 = e - s*96;
      int ciL = t3 / 3;
      int ki = t3 - ciL*3;
      unsigned short v0 = 0, v1 = 0, v2 = 0;
      if (s < 81) {
        int y = s / 9, x = s - y*9;
        int base = ciL*124 + (y+ki)*11 + x;
        v0 = InsU[base]; v1 = InsU[base+1]; v2 = InsU[base+2];
      }
      unsigned short* dst = AimU + s*296 + ciL*9 + ki*3;
      dst[0] = v0; dst[1] = v1; dst[2] = v2;
    }
    __syncthreads();
    // MFMA over this chunk: 9 K-steps of 32
    for (int ks = 0; ks < 9; ++ks) {
      int kk = ks*32 + kgrp*8;                       // within-chunk k for this lane group
      const float* wp = c2w + (size_t)col*2016 + cc*288 + kk;
      float4 wA = *(const float4*)wp;
      float4 wB = *(const float4*)(wp + 4);
      short8 bf;
      bf[0] = (short)f2bf(wA.x); bf[1] = (short)f2bf(wA.y);
      bf[2] = (short)f2bf(wA.z); bf[3] = (short)f2bf(wA.w);
      bf[4] = (short)f2bf(wB.x); bf[5] = (short)f2bf(wB.y);
      bf[6] = (short)f2bf(wB.z); bf[7] = (short)f2bf(wB.w);
#pragma unroll
      for (int mt = 0; mt < 6; ++mt) {
        short8 af = *(const short8*)(AimU + (mt*16 + (lane & 15))*296 + kk);
        acc[mt] = __builtin_amdgcn_mfma_f32_16x16x32_bf16(af, bf, acc[mt], 0, 0, 0);
      }
    }
  }
  // epilogue: bias + store B[b][oc][s]
  float bias = c2b[col];
  float* Bb = ws + OFF_B + (size_t)b*5184 + col*81;
#pragma unroll
  for (int mt = 0; mt < 6; ++mt) {
    int srow = mt*16 + kgrp*4;
#pragma unroll
    for (int r = 0; r < 4; ++r) {
      int s = srow + r;
      if (s < 81) Bb[s] = acc[mt][r] + bias;
    }
  }
}

// ---------------- kd6: BN2 partials per b (stats only; B already biased) ----------------
__global__ void kd6_bn2part(const float* ws_in, float* ws) {
  int b = blockIdx.x, t = threadIdx.x;  // t = channel (64 threads)
  const float* Bb = ws_in + OFF_B + (size_t)b * 5184 + t * 81;
  float S = 0.f, Q = 0.f;
  for (int s = 0; s < 81; ++s) {
    float v = Bb[s];
    S += v; Q += v * v;
  }
  ws[OFF_P + b*128 + t]      = S;
  ws[OFF_P + b*128 + 64 + t] = Q;
}

// ---------------- kd7: BN2 finalize ----------------
__global__ void kd7_bn2fin(float* ws, const float* bn2g, const float* bn2b) {
  int t = threadIdx.x;
  float S = 0.f, Q = 0.f;
  for (int b = 0; b < 1024; ++b) {
    S += ws[OFF_P + b*128 + t];
    Q += ws[OFF_P + b*128 + 64 + t];
  }
  float n = 82944.f;
  float mean = S / n;
  float var = Q / n - mean * mean;
  float sc = bn2g[t] * rsqrtf(var + EPS);
  ws[OFF_ST + 16 + t] = sc;
  ws[OFF_ST + 80 + t] = bn2b[t] - mean * sc;
}

// ---------------- kd8: BN2 apply + relu + transpose -> X0 [b][s][64] ----------------
__global__ __launch_bounds__(256) void kd8_tokens(float* ws) {
  int idx = blockIdx.x * 256 + threadIdx.x;
  if (idx >= 5308416) return;
  int o = idx % 64;
  int s = (idx / 64) % 81;
  int b = idx / 5184;
  float v = ws[OFF_ST + 16 + o] * ws[OFF_B + (size_t)b*5184 + o*81 + s] + ws[OFF_ST + 80 + o];
  ws[OFF_X0 + idx] = fmaxf(v, 0.f);
}

// ---------------- fa_layer v4: phase-local registers only; Z overlays dead P2||P3 ----------------
__global__ __launch_bounds__(256) void fa_layer(const float* ws_in, float* ws,
    const float* wq, const float* wk, const float* wv, const float* wgp, const float* wop,
    const float* ln1g, const float* ln1b, const float* gng, const float* gnb, int l)
{
  __shared__ __align__(16) float sm[17710];
  float* H   = sm;            // [81][68]
  float* P0  = sm + 5508;     // [81][34]
  float* P1  = sm + 8262;
  float* P2  = sm + 11016;
  float* P3  = sm + 13770;
  float* Zb  = sm + 11016;    // [81][68] overlay of P2||P3
  float* Wst = sm + 16524;    // [64][16]
  float* muv = sm + 17548;
  float* rsd = sm + 17629;
  const int tid = threadIdx.x;
  const int b = blockIdx.x;
  const float* xg = ws_in + OFF_X0 + (size_t)b * 5184;

  for (int u = tid; u < 5184; u += 256) {
    int s = u >> 6, d = u & 63;
    H[s*68 + d] = xg[u];
  }
  __syncthreads();
  if (tid < 81) {
    const float* xr = H + tid*68;
    float sv = 0.f;
    for (int d = 0; d < 64; ++d) sv += xr[d];
    float mean = sv * (1.f/64.f);
    float sq = 0.f;
    for (int d = 0; d < 64; ++d) { float dv = xr[d]-mean; sq += dv*dv; }
    muv[tid] = mean;
    rsd[tid] = rsqrtf(sq*(1.f/64.f) + EPS);
  }
  __syncthreads();
  for (int u = tid; u < 5184; u += 256) {
    int s = u >> 6, d = u & 63;
    H[s*68+d] = (H[s*68+d] - muv[s])*rsd[s]*ln1g[l*64+d] + ln1b[l*64+d];
  }

  const int c  = tid & 15;
  const int sg = tid >> 4;

  for (int p = 0; p < 2; ++p) {
    float* QB = p ? P1 : P0;
    float* KB = p ? P2 : P1;
    float* VB = p ? P3 : P2;
    for (int m = 0; m < 3; ++m) {
      const float* src = (m==0)? wq : (m==1)? wk : wv;
      float* dst = (m==0)? QB : (m==1)? KB : VB;
      for (int h2 = 0; h2 < 2; ++h2) {
        __syncthreads();
        const float* wbase = src + (size_t)(l*4 + 2*p + h2)*1024;
        for (int u = tid; u < 1024; u += 256) Wst[u] = wbase[u];
        __syncthreads();
        float acc[6] = {0.f,0.f,0.f,0.f,0.f,0.f};
        for (int d4 = 0; d4 < 16; ++d4) {
          float w0 = Wst[(d4*4+0)*16 + c];
          float w1 = Wst[(d4*4+1)*16 + c];
          float w2 = Wst[(d4*4+2)*16 + c];
          float w3 = Wst[(d4*4+3)*16 + c];
#pragma unroll
          for (int j = 0; j < 6; ++j) {
            int s = sg + 16*j;
            if (s < 81) {
              const float4 xv = *(const float4*)(H + s*68 + d4*4);
              acc[j] = fmaf(xv.x, w0, acc[j]);
              acc[j] = fmaf(xv.y, w1, acc[j]);
              acc[j] = fmaf(xv.z, w2, acc[j]);
              acc[j] = fmaf(xv.w, w3, acc[j]);
            }
          }
        }
#pragma unroll
        for (int j = 0; j < 6; ++j) {
          int s = sg + 16*j;
          if (s < 81) dst[s*34 + h2*16 + c] = acc[j];
        }
      }
    }
    __syncthreads();
    for (int u = tid; u < 2592; u += 256) {
      int m = u / 1296;
      int rem = u - m*1296;
      int h2 = rem / 648;
      int r = rem - h2*648;
      int pp = r & 7, s = r >> 3;
      float scale = (2.f*pp + 6.4f) / 22.4f;
      float xs = powf(scale, (float)s / 512.f);
      float invf = powf(10000.f, -(float)pp / 8.f);
      float ang = (float)s * invf;
      float cx = cosf(ang), sn = sinf(ang);
      float cu, su;
      if (m == 0) { cu = cx*xs; su = sn*xs; }
      else        { cu = cx/xs; su = sn/xs; }
      float* ptr = (m ? KB : QB) + s*34 + h2*16 + 2*pp;
      float a = ptr[0], bb2 = ptr[1];
      ptr[0] = a*cu - bb2*su;
      ptr[1] = bb2*cu + a*su;
    }
    __syncthreads();
    if (tid < 162) {
      int h2 = tid & 1, s = tid >> 1;
      int hd = 2*p + h2;
      float g = 1.f - expf(-3.4657359f + (float)hd * (-0.92419624f));
      float lg = log2f(g);
      float q[16];
#pragma unroll
      for (int k = 0; k < 16; ++k) q[k] = QB[s*34 + h2*16 + k];
      float yh[16];
#pragma unroll
      for (int v = 0; v < 16; ++v) yh[v] = 0.f;
      for (int tt = 0; tt <= s; ++tt) {
        const float* Kr = KB + tt*34 + h2*16;
        float a = 0.f;
#pragma unroll
        for (int k = 0; k < 16; ++k) a = fmaf(q[k], Kr[k], a);
        a *= exp2f((float)(s - tt) * lg);
        const float* Vr = VB + tt*34 + h2*16;
#pragma unroll
        for (int v = 0; v < 16; ++v) yh[v] = fmaf(a, Vr[v], yh[v]);
      }
      float sv = 0.f;
#pragma unroll
      for (int v = 0; v < 16; ++v) sv += yh[v];
      float mean = sv * (1.f/16.f);
      float sq = 0.f;
#pragma unroll
      for (int v = 0; v < 16; ++v) { float dv = yh[v]-mean; sq += dv*dv; }
      float rstd = rsqrtf(sq*(1.f/16.f) + EPS);
#pragma unroll
      for (int v = 0; v < 16; ++v) {
        int col = hd*16 + v;
        QB[s*34 + h2*16 + v] = (yh[v]-mean)*rstd*gng[l*64+col] + gnb[l*64+col];
      }
    }
  }

  for (int cc = 0; cc < 4; ++cc) {
    __syncthreads();
    for (int u = tid; u < 1024; u += 256)
      Wst[u] = wgp[(l*64 + (u>>4))*64 + cc*16 + (u&15)];
    __syncthreads();
    float acc[6] = {0.f,0.f,0.f,0.f,0.f,0.f};
    for (int d4 = 0; d4 < 16; ++d4) {
      float w0 = Wst[(d4*4+0)*16 + c];
      float w1 = Wst[(d4*4+1)*16 + c];
      float w2 = Wst[(d4*4+2)*16 + c];
      float w3 = Wst[(d4*4+3)*16 + c];
#pragma unroll
      for (int j = 0; j < 6; ++j) {
        int s = sg + 16*j;
        if (s < 81) {
          const float4 xv = *(const float4*)(H + s*68 + d4*4);
          acc[j] = fmaf(xv.x, w0, acc[j]);
          acc[j] = fmaf(xv.y, w1, acc[j]);
          acc[j] = fmaf(xv.z, w2, acc[j]);
          acc[j] = fmaf(xv.w, w3, acc[j]);
        }
      }
    }
    const float* gnb_ = (cc < 2 ? P0 : P1);
#pragma unroll
    for (int j = 0; j < 6; ++j) {
      int s = sg + 16*j;
      if (s < 81) {
        float gn = gnb_[s*34 + (cc&1)*16 + c];
        float g = acc[j];
        float sig = 1.f/(1.f+expf(-g));
        Zb[s*68 + cc*16 + c] = g*sig*gn;
      }
    }
  }

  float* yg = ws + OFF_Y + (size_t)b * 5184;
  for (int cc = 0; cc < 4; ++cc) {
    __syncthreads();
    for (int u = tid; u < 1024; u += 256)
      Wst[u] = wop[(l*64 + (u>>4))*64 + cc*16 + (u&15)];
    __syncthreads();
    float acc[6] = {0.f,0.f,0.f,0.f,0.f,0.f};
    for (int d4 = 0; d4 < 16; ++d4) {
      float w0 = Wst[(d4*4+0)*16 + c];
      float w1 = Wst[(d4*4+1)*16 + c];
      float w2 = Wst[(d4*4+2)*16 + c];
      float w3 = Wst[(d4*4+3)*16 + c];
#pragma unroll
      for (int j = 0; j < 6; ++j) {
        int s = sg + 16*j;
        if (s < 81) {
          const float4 xv = *(const float4*)(Zb + s*68 + d4*4);
          acc[j] = fmaf(xv.x, w0, acc[j]);
          acc[j] = fmaf(xv.y, w1, acc[j]);
          acc[j] = fmaf(xv.z, w2, acc[j]);
          acc[j] = fmaf(xv.w, w3, acc[j]);
        }
      }
    }
#pragma unroll
    for (int j = 0; j < 6; ++j) {
      int s = sg + 16*j;
      if (s < 81) {
        int u = s*64 + cc*16 + c;
        yg[u] = acc[j] + xg[u];
      }
    }
  }
}

// ---------------- ff_layer v3: two-half F1, 48.8 KB LDS ----------------
__global__ __launch_bounds__(256) void ff_layer(const float* ws_in, float* ws,
    const float* fw1, const float* fb1, const float* fw2, const float* fb2,
    const float* ln2g, const float* ln2b, int l)
{
  __shared__ __align__(16) float H2[81*68];
  __shared__ __align__(16) float F1h[81*68];
  __shared__ float Wst[1024];
  __shared__ float muv[81], rsd[81];
  const int tid = threadIdx.x;
  const int b = blockIdx.x;
  const float* yg = ws_in + OFF_Y + (size_t)b * 5184;

  for (int u = tid; u < 5184; u += 256) {
    int s = u >> 6, d = u & 63;
    H2[s*68 + d] = yg[u];
  }
  __syncthreads();
  if (tid < 81) {
    const float* xr = H2 + tid*68;
    float sv = 0.f;
    for (int d = 0; d < 64; ++d) sv += xr[d];
    float mean = sv * (1.f/64.f);
    float sq = 0.f;
    for (int d = 0; d < 64; ++d) { float dv = xr[d]-mean; sq += dv*dv; }
    muv[tid] = mean;
    rsd[tid] = rsqrtf(sq*(1.f/64.f) + EPS);
  }
  __syncthreads();
  for (int u = tid; u < 5184; u += 256) {
    int s = u >> 6, d = u & 63;
    H2[s*68+d] = (H2[s*68+d] - muv[s])*rsd[s]*ln2g[l*64+d] + ln2b[l*64+d];
  }

  const int c   = tid & 15;
  const int sg  = tid >> 4;
  const int c2  = tid & 63;
  const int sg2 = tid >> 6;
  float acc2[21];
#pragma unroll
  for (int i = 0; i < 21; ++i) acc2[i] = 0.f;

  for (int qq = 0; qq < 2; ++qq) {
    for (int fc = 0; fc < 4; ++fc) {
      __syncthreads();
      for (int u = tid; u < 1024; u += 256)
        Wst[u] = fw1[(l*64 + (u>>4))*128 + qq*64 + fc*16 + (u&15)];
      __syncthreads();
      float acc[6] = {0.f,0.f,0.f,0.f,0.f,0.f};
      for (int d4 = 0; d4 < 16; ++d4) {
        float w0 = Wst[(d4*4+0)*16 + c];
        float w1 = Wst[(d4*4+1)*16 + c];
        float w2 = Wst[(d4*4+2)*16 + c];
        float w3 = Wst[(d4*4+3)*16 + c];
#pragma unroll
        for (int j = 0; j < 6; ++j) {
          int s = sg + 16*j;
          if (s < 81) {
            const float4 xv = *(const float4*)(H2 + s*68 + d4*4);
            acc[j] = fmaf(xv.x, w0, acc[j]);
            acc[j] = fmaf(xv.y, w1, acc[j]);
            acc[j] = fmaf(xv.z, w2, acc[j]);
            acc[j] = fmaf(xv.w, w3, acc[j]);
          }
        }
      }
#pragma unroll
      for (int j = 0; j < 6; ++j) {
        int s = sg + 16*j;
        if (s < 81) {
          float pp = acc[j] + fb1[l*128 + qq*64 + fc*16 + c];
          F1h[s*68 + fc*16 + c] = 0.5f*pp*(1.f + erff(pp*0.70710678118f));
        }
      }
    }
    for (int fc = 0; fc < 4; ++fc) {
      __syncthreads();
      for (int u = tid; u < 1024; u += 256)
        Wst[u] = fw2[(l*128 + qq*64 + fc*16 + (u>>6))*64 + (u&63)];
      __syncthreads();
      float w[16];
#pragma unroll
      for (int f = 0; f < 16; ++f) w[f] = Wst[f*64 + c2];
#pragma unroll
      for (int i = 0; i < 21; ++i) {
        int s = sg2 + 4*i;
        if (s < 81) {
          const float4* fr = (const float4*)(F1h + s*68 + fc*16);
          float4 f0 = fr[0], f1 = fr[1], f2 = fr[2], f3 = fr[3];
          float a = acc2[i];
          a = fmaf(f0.x, w[0],  a); a = fmaf(f0.y, w[1],  a);
          a = fmaf(f0.z, w[2],  a); a = fmaf(f0.w, w[3],  a);
          a = fmaf(f1.x, w[4],  a); a = fmaf(f1.y, w[5],  a);
          a = fmaf(f1.z, w[6],  a); a = fmaf(f1.w, w[7],  a);
          a = fmaf(f2.x, w[8],  a); a = fmaf(f2.y, w[9],  a);
          a = fmaf(f2.z, w[10], a); a = fmaf(f2.w, w[11], a);
          a = fmaf(f3.x, w[12], a); a = fmaf(f3.y, w[13], a);
          a = fmaf(f3.z, w[14], a); a = fmaf(f3.w, w[15], a);
          acc2[i] = a;
        }
      }
    }
  }
  float* xg = ws + OFF_X0 + (size_t)b * 5184;
#pragma unroll
  for (int i = 0; i < 21; ++i) {
    int s = sg2 + 4*i;
    if (s < 81) {
      int u = s*64 + c2;
      xg[u] = acc2[i] + fb2[l*64 + c2] + yg[u];
    }
  }
}

// ---------------- fcls: classifier, one block per batch ----------------
__global__ __launch_bounds__(256) void fcls(const float* ws_in, const float* nn1w,
                                            const float* nn1b, float* out) {
  __shared__ float red[256];
  const int tid = threadIdx.x;
  const int b = blockIdx.x;
  const float* Xr = ws_in + OFF_X0 + (size_t)b * 5184;
  int c = tid & 15, chunk = tid >> 4;
  int i0 = chunk * 324;
  float a = 0.f;
  for (int i = 0; i < 324; ++i)
    a = fmaf(Xr[i0+i], nn1w[(size_t)(i0+i)*16 + c], a);
  red[tid] = a;
  __syncthreads();
  if (tid < 16) {
    float s = nn1b[tid];
#pragma unroll
    for (int j = 0; j < 16; ++j) s += red[j*16 + tid];
    out[b*16 + tid] = s;
  }
}

// ---------------- launch ----------------
extern "C" void kernel_launch(void* const* d_in, const int* in_sizes, int n_in,
                              void* d_out, int out_size, void* d_ws, size_t ws_size,
                              hipStream_t stream) {
  const float* X    = (const float*)d_in[0];
  const float* c3w  = (const float*)d_in[1];
  const float* c3b  = (const float*)d_in[2];
  const float* bn3g = (const float*)d_in[3];
  const float* bn3b = (const float*)d_in[4];
  const float* c2w  = (const float*)d_in[5];
  const float* c2b  = (const float*)d_in[6];
  const float* bn2g = (const float*)d_in[7];
  const float* bn2b = (const float*)d_in[8];
  const float* wq   = (const float*)d_in[9];
  const float* wk   = (const float*)d_in[10];
  const float* wv   = (const float*)d_in[11];
  const float* wg   = (const float*)d_in[12];
  const float* wo   = (const float*)d_in[13];
  const float* gng  = (const float*)d_in[14];
  const float* gnb  = (const float*)d_in[15];
  const float* ln1g = (const float*)d_in[16];
  const float* ln1b = (const float*)d_in[17];
  const float* ln2g = (const float*)d_in[18];
  const float* ln2b = (const float*)d_in[19];
  const float* fw1  = (const float*)d_in[20];
  const float* fb1  = (const float*)d_in[21];
  const float* fw2  = (const float*)d_in[22];
  const float* fb2  = (const float*)d_in[23];
  const float* nn1w = (const float*)d_in[24];
  const float* nn1b = (const float*)d_in[25];
  float* ws = (float*)d_ws;
  float* out = (float*)d_out;

  // conv stage
  kd1_conv1<<<108416, 256, 0, stream>>>(X, c3w, c3b, ws);
  kd2_bn1part<<<8192, 256, 0, stream>>>(ws, ws);
  kd3_bn1fin<<<1, 64, 0, stream>>>(ws, bn3g, bn3b);
  kd5_conv2_mfma<<<1024, 256, 0, stream>>>(ws, c2w, c2b, ws);
  kd6_bn2part<<<1024, 64, 0, stream>>>(ws, ws);
  kd7_bn2fin<<<1, 64, 0, stream>>>(ws, bn2g, bn2b);
  kd8_tokens<<<20736, 256, 0, stream>>>(ws);

  // transformer layers (fused per-batch)
  for (int l = 0; l < 2; ++l) {
    fa_layer<<<1024, 256, 0, stream>>>(ws, ws, wq, wk, wv, wg, wo,
                                       ln1g, ln1b, gng, gnb, l);
    ff_layer<<<1024, 256, 0, stream>>>(ws, ws, fw1, fb1, fw2, fb2,
                                       ln2g, ln2b, l);
  }

  fcls<<<1024, 256, 0, stream>>>(ws, nn1w, nn1b, out);
}

// Round 11
// 1629.554 us; speedup vs baseline: 1.7286x; 1.0159x over previous
//
#include <hip/hip_runtime.h>
#include <math.h>

#define EPS 1e-5f

// ---------------- float offsets in ws ----------------
#define OFF_A  0u          // conv1 out [1024][8][28][11][11] = 27,754,496 (dead after conv2)
#define OFF_X0 0u          // tokens x  [1024][81][64] = 5,308,416 (written after A dead)
#define OFF_Y  31850496u   // y [1024][81][64]
#define OFF_B  47775744u   // conv2 out [1024][64][81] = 5,308,416
#define OFF_P  53084160u   // partials  131,072 (dead after kd7 -> rotary table)
#define OFF_RT 53084160u   // rotary table [m 2][s 81][p 8][cu,su] = 2592 floats
#define OFF_ST 53215232u   // scale1[8] shift1[8] scale2[64] shift2[64]

typedef __attribute__((ext_vector_type(8))) short short8;
typedef __attribute__((ext_vector_type(4))) float f32x4;

__device__ inline unsigned short f2bf(float f) {
  unsigned int x = __float_as_uint(f);
  unsigned int r = x + 0x7fffu + ((x >> 16) & 1u);
  return (unsigned short)(r >> 16);
}

// ---------------- kd1: conv3d + bias -> A ----------------
__global__ __launch_bounds__(256) void kd1_conv1(const float* X, const float* c3w,
                                                 const float* c3b, float* ws) {
  int idx = blockIdx.x * 256 + threadIdx.x;
  if (idx >= 27754496) return;
  int pos = idx;
  int w = pos % 11; pos /= 11;
  int h = pos % 11; pos /= 11;
  int dd = pos % 28; pos /= 28;
  int o1 = pos % 8;
  int b = pos / 8;
  const float* Xb = X + (size_t)b * 5070;
  float a = c3b[o1];
#pragma unroll
  for (int kd = 0; kd < 3; ++kd)
#pragma unroll
    for (int kh = 0; kh < 3; ++kh)
#pragma unroll
      for (int kw = 0; kw < 3; ++kw)
        a = fmaf(Xb[(dd+kd)*169 + (h+kh)*13 + (w+kw)],
                 c3w[o1*27 + kd*9 + kh*3 + kw], a);
  ws[OFF_A + idx] = a;
}

// ---------------- kd2: BN1 partial sums per (b, o1) ----------------
__global__ __launch_bounds__(256) void kd2_bn1part(const float* ws_in, float* ws) {
  __shared__ float sS[256], sQ[256];
  int blk = blockIdx.x;               // b*8 + o1
  int tid = threadIdx.x;
  const float* Ab = ws_in + OFF_A + (size_t)blk * 3388;
  float S = 0.f, Q = 0.f;
  for (int i = tid; i < 3388; i += 256) {
    float v = Ab[i];
    S += v; Q += v * v;
  }
  sS[tid] = S; sQ[tid] = Q;
  __syncthreads();
  for (int st = 128; st > 0; st >>= 1) {
    if (tid < st) { sS[tid] += sS[tid+st]; sQ[tid] += sQ[tid+st]; }
    __syncthreads();
  }
  if (tid == 0) {
    ws[OFF_P + blk*2]     = sS[0];
    ws[OFF_P + blk*2 + 1] = sQ[0];
  }
}

// ---------------- kd3: BN1 finalize ----------------
__global__ void kd3_bn1fin(float* ws, const float* bn3g, const float* bn3b) {
  int t = threadIdx.x;
  if (t < 8) {
    float S = 0.f, Q = 0.f;
    for (int j = t; j < 8192; j += 8) {
      S += ws[OFF_P + j*2];
      Q += ws[OFF_P + j*2 + 1];
    }
    float n = 3469312.f;
    float mean = S / n;
    float var = Q / n - mean * mean;
    float sc = bn3g[t] * rsqrtf(var + EPS);
    ws[OFF_ST + t]     = sc;
    ws[OFF_ST + 8 + t] = bn3b[t] - mean * sc;
  }
}

// ---------------- kd5: conv2 as bf16 MFMA GEMM (per-batch) ----------------
__global__ __launch_bounds__(256) void kd5_conv2_mfma(const float* ws_in, const float* c2w,
                                                      const float* c2b, float* ws) {
  __shared__ unsigned short AimU[96*296];   // im2col tile, rows padded to 296
  __shared__ unsigned short InsU[32*124];   // BN1+relu'd conv1 slab chunk, bf16
  __shared__ float bn1[16];
  const int tid  = threadIdx.x;
  const int b    = blockIdx.x;
  const int wid  = tid >> 6;
  const int lane = tid & 63;
  if (tid < 16) bn1[tid] = ws_in[OFF_ST + tid];
  const float* Ab = ws_in + OFF_A + (size_t)b * 27104;   // [224][121]

  const int col = wid*16 + (lane & 15);     // this wave's output column (oc)
  const int kgrp = lane >> 4;               // 0..3
  f32x4 acc[6];
#pragma unroll
  for (int mt = 0; mt < 6; ++mt) acc[mt] = (f32x4){0.f,0.f,0.f,0.f};

  for (int cc = 0; cc < 7; ++cc) {
    __syncthreads();
    for (int e = tid; e < 3872; e += 256) {
      int ciL = e / 121, pos = e - ciL*121;
      int ci = cc*32 + ciL;
      int o1 = ci / 28;
      float raw = Ab[(size_t)ci*121 + pos];
      float v = fmaxf(bn1[o1]*raw + bn1[8+o1], 0.f);
      InsU[ciL*124 + pos] = f2bf(v);
    }
    __syncthreads();
    for (int e = tid; e < 9216; e += 256) {
      int s = e / 96;
      int t3 = e - s*96;
      int ciL = t3 / 3;
      int ki = t3 - ciL*3;
      unsigned short v0 = 0, v1 = 0, v2 = 0;
      if (s < 81) {
        int y = s / 9, x = s - y*9;
        int base = ciL*124 + (y+ki)*11 + x;
        v0 = InsU[base]; v1 = InsU[base+1]; v2 = InsU[base+2];
      }
      unsigned short* dst = AimU + s*296 + ciL*9 + ki*3;
      dst[0] = v0; dst[1] = v1; dst[2] = v2;
    }
    __syncthreads();
    for (int ks = 0; ks < 9; ++ks) {
      int kk = ks*32 + kgrp*8;
      const float* wp = c2w + (size_t)col*2016 + cc*288 + kk;
      float4 wA = *(const float4*)wp;
      float4 wB = *(const float4*)(wp + 4);
      short8 bf;
      bf[0] = (short)f2bf(wA.x); bf[1] = (short)f2bf(wA.y);
      bf[2] = (short)f2bf(wA.z); bf[3] = (short)f2bf(wA.w);
      bf[4] = (short)f2bf(wB.x); bf[5] = (short)f2bf(wB.y);
      bf[6] = (short)f2bf(wB.z); bf[7] = (short)f2bf(wB.w);
#pragma unroll
      for (int mt = 0; mt < 6; ++mt) {
        short8 af = *(const short8*)(AimU + (mt*16 + (lane & 15))*296 + kk);
        acc[mt] = __builtin_amdgcn_mfma_f32_16x16x32_bf16(af, bf, acc[mt], 0, 0, 0);
      }
    }
  }
  float bias = c2b[col];
  float* Bb = ws + OFF_B + (size_t)b*5184 + col*81;
#pragma unroll
  for (int mt = 0; mt < 6; ++mt) {
    int srow = mt*16 + kgrp*4;
#pragma unroll
    for (int r = 0; r < 4; ++r) {
      int s = srow + r;
      if (s < 81) Bb[s] = acc[mt][r] + bias;
    }
  }
}

// ---------------- kd6: BN2 partials per b ----------------
__global__ void kd6_bn2part(const float* ws_in, float* ws) {
  int b = blockIdx.x, t = threadIdx.x;  // t = channel (64 threads)
  const float* Bb = ws_in + OFF_B + (size_t)b * 5184 + t * 81;
  float S = 0.f, Q = 0.f;
  for (int s = 0; s < 81; ++s) {
    float v = Bb[s];
    S += v; Q += v * v;
  }
  ws[OFF_P + b*128 + t]      = S;
  ws[OFF_P + b*128 + 64 + t] = Q;
}

// ---------------- kd7: BN2 finalize ----------------
__global__ void kd7_bn2fin(float* ws, const float* bn2g, const float* bn2b) {
  int t = threadIdx.x;
  float S = 0.f, Q = 0.f;
  for (int b = 0; b < 1024; ++b) {
    S += ws[OFF_P + b*128 + t];
    Q += ws[OFF_P + b*128 + 64 + t];
  }
  float n = 82944.f;
  float mean = S / n;
  float var = Q / n - mean * mean;
  float sc = bn2g[t] * rsqrtf(var + EPS);
  ws[OFF_ST + 16 + t] = sc;
  ws[OFF_ST + 80 + t] = bn2b[t] - mean * sc;
}

// ---------------- k0rot: rotary tables -> OFF_RT (after kd7; OFF_P dead) ----------------
__global__ void k0rot(float* ws) {
  int i = blockIdx.x * 256 + threadIdx.x;   // (m, s, p)
  if (i >= 1296) return;
  int m = i / 648, r = i - m*648;
  int s = r >> 3, pp = r & 7;
  float scale = (2.f*pp + 6.4f) / 22.4f;
  float xs = powf(scale, (float)s / 512.f);
  float invf = powf(10000.f, -(float)pp / 8.f);
  float ang = (float)s * invf;
  float cx = cosf(ang), sn = sinf(ang);
  float cu = m ? cx/xs : cx*xs;
  float su = m ? sn/xs : sn*xs;
  ws[OFF_RT + i*2]     = cu;
  ws[OFF_RT + i*2 + 1] = su;
}

// ---------------- kd8: BN2 apply + relu + transpose -> X0 [b][s][64] ----------------
__global__ __launch_bounds__(256) void kd8_tokens(float* ws) {
  int idx = blockIdx.x * 256 + threadIdx.x;
  if (idx >= 5308416) return;
  int o = idx % 64;
  int s = (idx / 64) % 81;
  int b = idx / 5184;
  float v = ws[OFF_ST + 16 + o] * ws[OFF_B + (size_t)b*5184 + o*81 + s] + ws[OFF_ST + 80 + o];
  ws[OFF_X0 + idx] = fmaxf(v, 0.f);
}

// ---------------- fa_layer v5: direct-global weights, 10 barriers, rotary table ----------------
// sm: H[81*68] | P0[81*34] | P1 | P2 | P3 | muv[81] | rsd[81]  (Z overlays P2||P3)
__global__ __launch_bounds__(256) void fa_layer(const float* ws_in, float* ws,
    const float* wq, const float* wk, const float* wv, const float* wgp, const float* wop,
    const float* ln1g, const float* ln1b, const float* gng, const float* gnb, int l)
{
  __shared__ __align__(16) float sm[16686];
  float* H   = sm;            // [81][68]
  float* P0  = sm + 5508;     // [81][34]
  float* P1  = sm + 8262;
  float* P2  = sm + 11016;
  float* P3  = sm + 13770;
  float* Zb  = sm + 11016;    // [81][68] overlay of P2||P3
  float* muv = sm + 16524;
  float* rsd = sm + 16605;
  const int tid = threadIdx.x;
  const int b = blockIdx.x;
  const float* xg = ws_in + OFF_X0 + (size_t)b * 5184;
  const float* rtab = ws_in + OFF_RT;

  for (int u = tid; u < 5184; u += 256) {
    int s = u >> 6, d = u & 63;
    H[s*68 + d] = xg[u];
  }
  __syncthreads();                                           // 1
  if (tid < 81) {
    const float* xr = H + tid*68;
    float sv = 0.f;
    for (int d = 0; d < 64; ++d) sv += xr[d];
    float mean = sv * (1.f/64.f);
    float sq = 0.f;
    for (int d = 0; d < 64; ++d) { float dv = xr[d]-mean; sq += dv*dv; }
    muv[tid] = mean;
    rsd[tid] = rsqrtf(sq*(1.f/64.f) + EPS);
  }
  __syncthreads();                                           // 2
  for (int u = tid; u < 5184; u += 256) {
    int s = u >> 6, d = u & 63;
    H[s*68+d] = (H[s*68+d] - muv[s])*rsd[s]*ln1g[l*64+d] + ln1b[l*64+d];
  }
  __syncthreads();                                           // 3

  const int c  = tid & 15;
  const int sg = tid >> 4;

  for (int p = 0; p < 2; ++p) {
    float* QB = p ? P1 : P0;
    float* KB = p ? P2 : P1;
    float* VB = p ? P3 : P2;
    // 6 projection sub-GEMMs, weights direct from global, no internal barriers
    for (int m = 0; m < 3; ++m) {
      const float* src = (m==0)? wq : (m==1)? wk : wv;
      float* dst = (m==0)? QB : (m==1)? KB : VB;
      for (int h2 = 0; h2 < 2; ++h2) {
        const float* wbase = src + (size_t)(l*4 + 2*p + h2)*1024 + c;
        float acc[6] = {0.f,0.f,0.f,0.f,0.f,0.f};
#pragma unroll 4
        for (int d4 = 0; d4 < 16; ++d4) {
          float w0 = wbase[(d4*4+0)*16];
          float w1 = wbase[(d4*4+1)*16];
          float w2 = wbase[(d4*4+2)*16];
          float w3 = wbase[(d4*4+3)*16];
#pragma unroll
          for (int j = 0; j < 6; ++j) {
            int s = sg + 16*j;
            if (s < 81) {
              const float4 xv = *(const float4*)(H + s*68 + d4*4);
              acc[j] = fmaf(xv.x, w0, acc[j]);
              acc[j] = fmaf(xv.y, w1, acc[j]);
              acc[j] = fmaf(xv.z, w2, acc[j]);
              acc[j] = fmaf(xv.w, w3, acc[j]);
            }
          }
        }
#pragma unroll
        for (int j = 0; j < 6; ++j) {
          int s = sg + 16*j;
          if (s < 81) dst[s*34 + h2*16 + c] = acc[j];
        }
      }
    }
    __syncthreads();                                         // 4 / 7
    for (int u = tid; u < 2592; u += 256) {
      int m = u / 1296;
      int rem = u - m*1296;
      int h2 = rem / 648;
      int r2 = rem - h2*648;
      int pp = r2 & 7, s = r2 >> 3;
      const float* rt = rtab + (m*648 + s*8 + pp)*2;
      float cu = rt[0], su = rt[1];
      float* ptr = (m ? KB : QB) + s*34 + h2*16 + 2*pp;
      float a = ptr[0], bb2 = ptr[1];
      ptr[0] = a*cu - bb2*su;
      ptr[1] = bb2*cu + a*su;
    }
    __syncthreads();                                         // 5 / 8
    if (tid < 162) {
      int h2 = tid & 1, s = tid >> 1;
      int hd = 2*p + h2;
      float g = 1.f - expf(-3.4657359f + (float)hd * (-0.92419624f));
      float lg = log2f(g);
      float q[16];
#pragma unroll
      for (int k = 0; k < 16; ++k) q[k] = QB[s*34 + h2*16 + k];
      float yh[16];
#pragma unroll
      for (int v = 0; v < 16; ++v) yh[v] = 0.f;
      for (int tt = 0; tt <= s; ++tt) {
        const float* Kr = KB + tt*34 + h2*16;
        float a = 0.f;
#pragma unroll
        for (int k = 0; k < 16; ++k) a = fmaf(q[k], Kr[k], a);
        a *= exp2f((float)(s - tt) * lg);
        const float* Vr = VB + tt*34 + h2*16;
#pragma unroll
        for (int v = 0; v < 16; ++v) yh[v] = fmaf(a, Vr[v], yh[v]);
      }
      float sv = 0.f;
#pragma unroll
      for (int v = 0; v < 16; ++v) sv += yh[v];
      float mean = sv * (1.f/16.f);
      float sq = 0.f;
#pragma unroll
      for (int v = 0; v < 16; ++v) { float dv = yh[v]-mean; sq += dv*dv; }
      float rstd = rsqrtf(sq*(1.f/16.f) + EPS);
#pragma unroll
      for (int v = 0; v < 16; ++v) {
        int col = hd*16 + v;
        QB[s*34 + h2*16 + v] = (yh[v]-mean)*rstd*gng[l*64+col] + gnb[l*64+col];
      }
    }
    __syncthreads();                                         // 6 / 9
  }
  // P0 = gn heads 0,1; P1 = gn heads 2,3; P2/P3 dead -> Z region

  for (int cc = 0; cc < 4; ++cc) {
    const float* wbase = wgp + (size_t)l*4096 + cc*16 + c;
    float acc[6] = {0.f,0.f,0.f,0.f,0.f,0.f};
#pragma unroll 4
    for (int d4 = 0; d4 < 16; ++d4) {
      float w0 = wbase[(d4*4+0)*64];
      float w1 = wbase[(d4*4+1)*64];
      float w2 = wbase[(d4*4+2)*64];
      float w3 = wbase[(d4*4+3)*64];
#pragma unroll
      for (int j = 0; j < 6; ++j) {
        int s = sg + 16*j;
        if (s < 81) {
          const float4 xv = *(const float4*)(H + s*68 + d4*4);
          acc[j] = fmaf(xv.x, w0, acc[j]);
          acc[j] = fmaf(xv.y, w1, acc[j]);
          acc[j] = fmaf(xv.z, w2, acc[j]);
          acc[j] = fmaf(xv.w, w3, acc[j]);
        }
      }
    }
    const float* gnb_ = (cc < 2 ? P0 : P1);
#pragma unroll
    for (int j = 0; j < 6; ++j) {
      int s = sg + 16*j;
      if (s < 81) {
        float gn = gnb_[s*34 + (cc&1)*16 + c];
        float g = acc[j];
        float sig = 1.f/(1.f+expf(-g));
        Zb[s*68 + cc*16 + c] = g*sig*gn;
      }
    }
  }
  __syncthreads();                                           // 10

  float* yg = ws + OFF_Y + (size_t)b * 5184;
  for (int cc = 0; cc < 4; ++cc) {
    const float* wbase = wop + (size_t)l*4096 + cc*16 + c;
    float acc[6] = {0.f,0.f,0.f,0.f,0.f,0.f};
#pragma unroll 4
    for (int d4 = 0; d4 < 16; ++d4) {
      float w0 = wbase[(d4*4+0)*64];
      float w1 = wbase[(d4*4+1)*64];
      float w2 = wbase[(d4*4+2)*64];
      float w3 = wbase[(d4*4+3)*64];
#pragma unroll
      for (int j = 0; j < 6; ++j) {
        int s = sg + 16*j;
        if (s < 81) {
          const float4 xv = *(const float4*)(Zb + s*68 + d4*4);
          acc[j] = fmaf(xv.x, w0, acc[j]);
          acc[j] = fmaf(xv.y, w1, acc[j]);
          acc[j] = fmaf(xv.z, w2, acc[j]);
          acc[j] = fmaf(xv.w, w3, acc[j]);
        }
      }
    }
#pragma unroll
    for (int j = 0; j < 6; ++j) {
      int s = sg + 16*j;
      if (s < 81) {
        int u = s*64 + cc*16 + c;
        yg[u] = acc[j] + xg[u];
      }
    }
  }
}

// ---------------- ff_layer v4: direct-global weights, 7 barriers, 43.7 KB LDS ----------------
__global__ __launch_bounds__(256) void ff_layer(const float* ws_in, float* ws,
    const float* fw1, const float* fb1, const float* fw2, const float* fb2,
    const float* ln2g, const float* ln2b, int l)
{
  __shared__ __align__(16) float H2[81*68];
  __shared__ __align__(16) float F1h[81*68];
  __shared__ float muv[81], rsd[81];
  const int tid = threadIdx.x;
  const int b = blockIdx.x;
  const float* yg = ws_in + OFF_Y + (size_t)b * 5184;

  for (int u = tid; u < 5184; u += 256) {
    int s = u >> 6, d = u & 63;
    H2[s*68 + d] = yg[u];
  }
  __syncthreads();
  if (tid < 81) {
    const float* xr = H2 + tid*68;
    float sv = 0.f;
    for (int d = 0; d < 64; ++d) sv += xr[d];
    float mean = sv * (1.f/64.f);
    float sq = 0.f;
    for (int d = 0; d < 64; ++d) { float dv = xr[d]-mean; sq += dv*dv; }
    muv[tid] = mean;
    rsd[tid] = rsqrtf(sq*(1.f/64.f) + EPS);
  }
  __syncthreads();
  for (int u = tid; u < 5184; u += 256) {
    int s = u >> 6, d = u & 63;
    H2[s*68+d] = (H2[s*68+d] - muv[s])*rsd[s]*ln2g[l*64+d] + ln2b[l*64+d];
  }
  __syncthreads();

  const int c   = tid & 15;
  const int sg  = tid >> 4;
  const int c2  = tid & 63;
  const int sg2 = tid >> 6;
  float acc2[21];
#pragma unroll
  for (int i = 0; i < 21; ++i) acc2[i] = 0.f;

  for (int qq = 0; qq < 2; ++qq) {
    // ffn1 half (4 col chunks, no internal barriers)
    for (int fc = 0; fc < 4; ++fc) {
      const float* wbase = fw1 + (size_t)l*8192 + qq*64 + fc*16 + c;
      float acc[6] = {0.f,0.f,0.f,0.f,0.f,0.f};
#pragma unroll 4
      for (int d4 = 0; d4 < 16; ++d4) {
        float w0 = wbase[(d4*4+0)*128];
        float w1 = wbase[(d4*4+1)*128];
        float w2 = wbase[(d4*4+2)*128];
        float w3 = wbase[(d4*4+3)*128];
#pragma unroll
        for (int j = 0; j < 6; ++j) {
          int s = sg + 16*j;
          if (s < 81) {
            const float4 xv = *(const float4*)(H2 + s*68 + d4*4);
            acc[j] = fmaf(xv.x, w0, acc[j]);
            acc[j] = fmaf(xv.y, w1, acc[j]);
            acc[j] = fmaf(xv.z, w2, acc[j]);
            acc[j] = fmaf(xv.w, w3, acc[j]);
          }
        }
      }
#pragma unroll
      for (int j = 0; j < 6; ++j) {
        int s = sg + 16*j;
        if (s < 81) {
          float pp = acc[j] + fb1[l*128 + qq*64 + fc*16 + c];
          F1h[s*68 + fc*16 + c] = 0.5f*pp*(1.f + erff(pp*0.70710678118f));
        }
      }
    }
    __syncthreads();
    // ffn2 half accumulate (no internal barriers)
    for (int fc = 0; fc < 4; ++fc) {
      const float* wb2 = fw2 + (size_t)(l*128 + qq*64 + fc*16)*64 + c2;
      float w[16];
#pragma unroll
      for (int f = 0; f < 16; ++f) w[f] = wb2[f*64];
#pragma unroll
      for (int i = 0; i < 21; ++i) {
        int s = sg2 + 4*i;
        if (s < 81) {
          const float4* fr = (const float4*)(F1h + s*68 + fc*16);
          float4 f0 = fr[0], f1 = fr[1], f2 = fr[2], f3 = fr[3];
          float a = acc2[i];
          a = fmaf(f0.x, w[0],  a); a = fmaf(f0.y, w[1],  a);
          a = fmaf(f0.z, w[2],  a); a = fmaf(f0.w, w[3],  a);
          a = fmaf(f1.x, w[4],  a); a = fmaf(f1.y, w[5],  a);
          a = fmaf(f1.z, w[6],  a); a = fmaf(f1.w, w[7],  a);
          a = fmaf(f2.x, w[8],  a); a = fmaf(f2.y, w[9],  a);
          a = fmaf(f2.z, w[10], a); a = fmaf(f2.w, w[11], a);
          a = fmaf(f3.x, w[12], a); a = fmaf(f3.y, w[13], a);
          a = fmaf(f3.z, w[14], a); a = fmaf(f3.w, w[15], a);
          acc2[i] = a;
        }
      }
    }
    __syncthreads();
  }
  float* xg = ws + OFF_X0 + (size_t)b * 5184;
#pragma unroll
  for (int i = 0; i < 21; ++i) {
    int s = sg2 + 4*i;
    if (s < 81) {
      int u = s*64 + c2;
      xg[u] = acc2[i] + fb2[l*64 + c2] + yg[u];
    }
  }
}

// ---------------- fcls: classifier, one block per batch ----------------
__global__ __launch_bounds__(256) void fcls(const float* ws_in, const float* nn1w,
                                            const float* nn1b, float* out) {
  __shared__ float red[256];
  const int tid = threadIdx.x;
  const int b = blockIdx.x;
  const float* Xr = ws_in + OFF_X0 + (size_t)b * 5184;
  int c = tid & 15, chunk = tid >> 4;
  int i0 = chunk * 324;
  float a = 0.f;
  for (int i = 0; i < 324; ++i)
    a = fmaf(Xr[i0+i], nn1w[(size_t)(i0+i)*16 + c], a);
  red[tid] = a;
  __syncthreads();
  if (tid < 16) {
    float s = nn1b[tid];
#pragma unroll
    for (int j = 0; j < 16; ++j) s += red[j*16 + tid];
    out[b*16 + tid] = s;
  }
}

// ---------------- launch ----------------
extern "C" void kernel_launch(void* const* d_in, const int* in_sizes, int n_in,
                              void* d_out, int out_size, void* d_ws, size_t ws_size,
                              hipStream_t stream) {
  const float* X    = (const float*)d_in[0];
  const float* c3w  = (const float*)d_in[1];
  const float* c3b  = (const float*)d_in[2];
  const float* bn3g = (const float*)d_in[3];
  const float* bn3b = (const float*)d_in[4];
  const float* c2w  = (const float*)d_in[5];
  const float* c2b  = (const float*)d_in[6];
  const float* bn2g = (const float*)d_in[7];
  const float* bn2b = (const float*)d_in[8];
  const float* wq   = (const float*)d_in[9];
  const float* wk   = (const float*)d_in[10];
  const float* wv   = (const float*)d_in[11];
  const float* wg   = (const float*)d_in[12];
  const float* wo   = (const float*)d_in[13];
  const float* gng  = (const float*)d_in[14];
  const float* gnb  = (const float*)d_in[15];
  const float* ln1g = (const float*)d_in[16];
  const float* ln1b = (const float*)d_in[17];
  const float* ln2g = (const float*)d_in[18];
  const float* ln2b = (const float*)d_in[19];
  const float* fw1  = (const float*)d_in[20];
  const float* fb1  = (const float*)d_in[21];
  const float* fw2  = (const float*)d_in[22];
  const float* fb2  = (const float*)d_in[23];
  const float* nn1w = (const float*)d_in[24];
  const float* nn1b = (const float*)d_in[25];
  float* ws = (float*)d_ws;
  float* out = (float*)d_out;

  // conv stage
  kd1_conv1<<<108416, 256, 0, stream>>>(X, c3w, c3b, ws);
  kd2_bn1part<<<8192, 256, 0, stream>>>(ws, ws);
  kd3_bn1fin<<<1, 64, 0, stream>>>(ws, bn3g, bn3b);
  kd5_conv2_mfma<<<1024, 256, 0, stream>>>(ws, c2w, c2b, ws);
  kd6_bn2part<<<1024, 64, 0, stream>>>(ws, ws);
  kd7_bn2fin<<<1, 64, 0, stream>>>(ws, bn2g, bn2b);
  k0rot<<<6, 256, 0, stream>>>(ws);          // OFF_P dead after kd7
  kd8_tokens<<<20736, 256, 0, stream>>>(ws);

  // transformer layers (fused per-batch)
  for (int l = 0; l < 2; ++l) {
    fa_layer<<<1024, 256, 0, stream>>>(ws, ws, wq, wk, wv, wg, wo,
                                       ln1g, ln1b, gng, gnb, l);
    ff_layer<<<1024, 256, 0, stream>>>(ws, ws, fw1, fb1, fw2, fb2,
                                       ln2g, ln2b, l);
  }

  fcls<<<1024, 256, 0, stream>>>(ws, nn1w, nn1b, out);
}

// Round 12
// 1016.901 us; speedup vs baseline: 2.7701x; 1.6025x over previous
//
#include <hip/hip_runtime.h>
#include <math.h>

#define EPS 1e-5f

// ---------------- float offsets in ws ----------------
#define OFF_A  0u          // conv1 out (dead after conv2)
#define OFF_X0 0u          // tokens x [1024][81][64]
#define OFF_Y  31850496u   // y [1024][81][64]
#define OFF_B  47775744u   // conv2 out; after kd8: packed bf16 weights
#define OFF_P  53084160u   // partials (dead after kd7 -> rotary table)
#define OFF_RT 53084160u   // rotary table
#define OFF_ST 53215232u   // scale1[8] shift1[8] scale2[64] shift2[64]

// packed bf16 weight offsets (ushort units, base = (ushort*)(ws+OFF_B))
#define WB_QKV 0u          // [(l*2+p)*96+col]*64+k          (24576)
#define WB_WG  24576u      // [(l*64+col)]*64+k              (8192)
#define WB_WO  32768u      // [(l*64+col)]*64+k              (8192)
#define WB_FW1 40960u      // [(l*128+col)]*64+k             (16384)
#define WB_FW2 57344u      // [(l*64+col)]*128+k             (16384)

typedef __attribute__((ext_vector_type(8))) short short8;
typedef __attribute__((ext_vector_type(4))) float f32x4;

__device__ inline unsigned short f2bf(float f) {
  unsigned int x = __float_as_uint(f);
  unsigned int r = x + 0x7fffu + ((x >> 16) & 1u);
  return (unsigned short)(r >> 16);
}

// ---------------- kd1: conv3d + bias -> A ----------------
__global__ __launch_bounds__(256) void kd1_conv1(const float* X, const float* c3w,
                                                 const float* c3b, float* ws) {
  int idx = blockIdx.x * 256 + threadIdx.x;
  if (idx >= 27754496) return;
  int pos = idx;
  int w = pos % 11; pos /= 11;
  int h = pos % 11; pos /= 11;
  int dd = pos % 28; pos /= 28;
  int o1 = pos % 8;
  int b = pos / 8;
  const float* Xb = X + (size_t)b * 5070;
  float a = c3b[o1];
#pragma unroll
  for (int kd = 0; kd < 3; ++kd)
#pragma unroll
    for (int kh = 0; kh < 3; ++kh)
#pragma unroll
      for (int kw = 0; kw < 3; ++kw)
        a = fmaf(Xb[(dd+kd)*169 + (h+kh)*13 + (w+kw)],
                 c3w[o1*27 + kd*9 + kh*3 + kw], a);
  ws[OFF_A + idx] = a;
}

// ---------------- kd2: BN1 partial sums ----------------
__global__ __launch_bounds__(256) void kd2_bn1part(const float* ws_in, float* ws) {
  __shared__ float sS[256], sQ[256];
  int blk = blockIdx.x;
  int tid = threadIdx.x;
  const float* Ab = ws_in + OFF_A + (size_t)blk * 3388;
  float S = 0.f, Q = 0.f;
  for (int i = tid; i < 3388; i += 256) {
    float v = Ab[i];
    S += v; Q += v * v;
  }
  sS[tid] = S; sQ[tid] = Q;
  __syncthreads();
  for (int st = 128; st > 0; st >>= 1) {
    if (tid < st) { sS[tid] += sS[tid+st]; sQ[tid] += sQ[tid+st]; }
    __syncthreads();
  }
  if (tid == 0) {
    ws[OFF_P + blk*2]     = sS[0];
    ws[OFF_P + blk*2 + 1] = sQ[0];
  }
}

// ---------------- kd3: BN1 finalize ----------------
__global__ void kd3_bn1fin(float* ws, const float* bn3g, const float* bn3b) {
  int t = threadIdx.x;
  if (t < 8) {
    float S = 0.f, Q = 0.f;
    for (int j = t; j < 8192; j += 8) {
      S += ws[OFF_P + j*2];
      Q += ws[OFF_P + j*2 + 1];
    }
    float n = 3469312.f;
    float mean = S / n;
    float var = Q / n - mean * mean;
    float sc = bn3g[t] * rsqrtf(var + EPS);
    ws[OFF_ST + t]     = sc;
    ws[OFF_ST + 8 + t] = bn3b[t] - mean * sc;
  }
}

// ---------------- kd5: conv2 as bf16 MFMA GEMM ----------------
__global__ __launch_bounds__(256) void kd5_conv2_mfma(const float* ws_in, const float* c2w,
                                                      const float* c2b, float* ws) {
  __shared__ unsigned short AimU[96*296];
  __shared__ unsigned short InsU[32*124];
  __shared__ float bn1[16];
  const int tid  = threadIdx.x;
  const int b    = blockIdx.x;
  const int wid  = tid >> 6;
  const int lane = tid & 63;
  if (tid < 16) bn1[tid] = ws_in[OFF_ST + tid];
  const float* Ab = ws_in + OFF_A + (size_t)b * 27104;

  const int col = wid*16 + (lane & 15);
  const int kgrp = lane >> 4;
  f32x4 acc[6];
#pragma unroll
  for (int mt = 0; mt < 6; ++mt) acc[mt] = (f32x4){0.f,0.f,0.f,0.f};

  for (int cc = 0; cc < 7; ++cc) {
    __syncthreads();
    for (int e = tid; e < 3872; e += 256) {
      int ciL = e / 121, pos = e - ciL*121;
      int ci = cc*32 + ciL;
      int o1 = ci / 28;
      float raw = Ab[(size_t)ci*121 + pos];
      float v = fmaxf(bn1[o1]*raw + bn1[8+o1], 0.f);
      InsU[ciL*124 + pos] = f2bf(v);
    }
    __syncthreads();
    for (int e = tid; e < 9216; e += 256) {
      int s = e / 96;
      int t3 = e - s*96;
      int ciL = t3 / 3;
      int ki = t3 - ciL*3;
      unsigned short v0 = 0, v1 = 0, v2 = 0;
      if (s < 81) {
        int y = s / 9, x = s - y*9;
        int base = ciL*124 + (y+ki)*11 + x;
        v0 = InsU[base]; v1 = InsU[base+1]; v2 = InsU[base+2];
      }
      unsigned short* dst = AimU + s*296 + ciL*9 + ki*3;
      dst[0] = v0; dst[1] = v1; dst[2] = v2;
    }
    __syncthreads();
    for (int ks = 0; ks < 9; ++ks) {
      int kk = ks*32 + kgrp*8;
      const float* wp = c2w + (size_t)col*2016 + cc*288 + kk;
      float4 wA = *(const float4*)wp;
      float4 wB = *(const float4*)(wp + 4);
      short8 bf;
      bf[0] = (short)f2bf(wA.x); bf[1] = (short)f2bf(wA.y);
      bf[2] = (short)f2bf(wA.z); bf[3] = (short)f2bf(wA.w);
      bf[4] = (short)f2bf(wB.x); bf[5] = (short)f2bf(wB.y);
      bf[6] = (short)f2bf(wB.z); bf[7] = (short)f2bf(wB.w);
#pragma unroll
      for (int mt = 0; mt < 6; ++mt) {
        short8 af = *(const short8*)(AimU + (mt*16 + (lane & 15))*296 + kk);
        acc[mt] = __builtin_amdgcn_mfma_f32_16x16x32_bf16(af, bf, acc[mt], 0, 0, 0);
      }
    }
  }
  float bias = c2b[col];
  float* Bb = ws + OFF_B + (size_t)b*5184 + col*81;
#pragma unroll
  for (int mt = 0; mt < 6; ++mt) {
    int srow = mt*16 + kgrp*4;
#pragma unroll
    for (int r = 0; r < 4; ++r) {
      int s = srow + r;
      if (s < 81) Bb[s] = acc[mt][r] + bias;
    }
  }
}

// ---------------- kd6: BN2 partials ----------------
__global__ void kd6_bn2part(const float* ws_in, float* ws) {
  int b = blockIdx.x, t = threadIdx.x;
  const float* Bb = ws_in + OFF_B + (size_t)b * 5184 + t * 81;
  float S = 0.f, Q = 0.f;
  for (int s = 0; s < 81; ++s) {
    float v = Bb[s];
    S += v; Q += v * v;
  }
  ws[OFF_P + b*128 + t]      = S;
  ws[OFF_P + b*128 + 64 + t] = Q;
}

// ---------------- kd7: BN2 finalize ----------------
__global__ void kd7_bn2fin(float* ws, const float* bn2g, const float* bn2b) {
  int t = threadIdx.x;
  float S = 0.f, Q = 0.f;
  for (int b = 0; b < 1024; ++b) {
    S += ws[OFF_P + b*128 + t];
    Q += ws[OFF_P + b*128 + 64 + t];
  }
  float n = 82944.f;
  float mean = S / n;
  float var = Q / n - mean * mean;
  float sc = bn2g[t] * rsqrtf(var + EPS);
  ws[OFF_ST + 16 + t] = sc;
  ws[OFF_ST + 80 + t] = bn2b[t] - mean * sc;
}

// ---------------- k0rot: rotary tables ----------------
__global__ void k0rot(float* ws) {
  int i = blockIdx.x * 256 + threadIdx.x;
  if (i >= 1296) return;
  int m = i / 648, r = i - m*648;
  int s = r >> 3, pp = r & 7;
  float scale = (2.f*pp + 6.4f) / 22.4f;
  float xs = powf(scale, (float)s / 512.f);
  float invf = powf(10000.f, -(float)pp / 8.f);
  float ang = (float)s * invf;
  float cx = cosf(ang), sn = sinf(ang);
  float cu = m ? cx/xs : cx*xs;
  float su = m ? sn/xs : sn*xs;
  ws[OFF_RT + i*2]     = cu;
  ws[OFF_RT + i*2 + 1] = su;
}

// ---------------- kd8: BN2 apply + relu + transpose -> X0 ----------------
__global__ __launch_bounds__(256) void kd8_tokens(float* ws) {
  int idx = blockIdx.x * 256 + threadIdx.x;
  if (idx >= 5308416) return;
  int o = idx % 64;
  int s = (idx / 64) % 81;
  int b = idx / 5184;
  float v = ws[OFF_ST + 16 + o] * ws[OFF_B + (size_t)b*5184 + o*81 + s] + ws[OFF_ST + 80 + o];
  ws[OFF_X0 + idx] = fmaxf(v, 0.f);
}

// ---------------- k0pack: bf16 col-major weight pack into dead OFF_B ----------------
__global__ void k0pack(const float* wq, const float* wk, const float* wv,
                       const float* wg, const float* wo, const float* fw1,
                       const float* fw2, float* ws) {
  int i = blockIdx.x * 256 + threadIdx.x;
  unsigned short* wb = (unsigned short*)(ws + OFF_B);
  if (i < 24576) {                      // QKV: [(l*2+p)*96+col][k]
    int l = i / 12288, r = i % 12288;
    int p = r / 6144; r %= 6144;
    int col = r / 64, k = r % 64;
    int m = col >> 5, h2 = (col >> 4) & 1, kk = col & 15;
    const float* src = (m==0) ? wq : (m==1) ? wk : wv;
    wb[i] = f2bf(src[((l*4 + 2*p + h2)*64 + k)*16 + kk]);
  } else if (i < 32768) {               // WG: [(l*64+col)][k]
    int j = i - 24576;
    int l = j / 4096, col = (j / 64) & 63, k = j & 63;
    wb[i] = f2bf(wg[(l*64 + k)*64 + col]);
  } else if (i < 40960) {               // WO
    int j = i - 32768;
    int l = j / 4096, col = (j / 64) & 63, k = j & 63;
    wb[i] = f2bf(wo[(l*64 + k)*64 + col]);
  } else if (i < 57344) {               // FW1: [(l*128+col)][k]
    int j = i - 40960;
    int l = j / 8192, col = (j / 64) % 128, k = j & 63;
    wb[i] = f2bf(fw1[(l*64 + k)*128 + col]);
  } else if (i < 73728) {               // FW2: [(l*64+col)][k 128]
    int j = i - 57344;
    int l = j / 8192, col = (j / 128) & 63, k = j % 128;
    wb[i] = f2bf(fw2[(l*128 + k)*64 + col]);
  }
}

// ---------------- fa_layer v6: MFMA projections/gate/wo; scalar retention ----------------
// sm floats: Hb(ush[96][80])=3840 | P0 | P1 | P2 | P3 (each 2754) | muv 81 | rsd 81
// XT fp32 overlays P0/P1; Zb bf16 [96][80] overlays P2/P3.
__global__ __launch_bounds__(256) void fa_layer(const float* ws_in, float* ws,
    const float* ln1g, const float* ln1b, const float* gng, const float* gnb, int l)
{
  __shared__ __align__(16) float sm[15018];
  unsigned short* Hb = (unsigned short*)sm;       // [96][80]
  float* P0 = sm + 3840;
  float* P1 = sm + 6594;
  float* P2 = sm + 9348;
  float* P3 = sm + 12102;
  float* XT = sm + 3840;                          // [81][64] overlay P0/P1
  unsigned short* Zb = (unsigned short*)(sm + 9348);  // [96][80] overlay P2/P3
  float* muv = sm + 14856;
  float* rsd = sm + 14937;
  const int tid  = threadIdx.x;
  const int b    = blockIdx.x;
  const int wid  = tid >> 6;
  const int lane = tid & 63;
  const int lane15 = lane & 15;
  const int kgrp   = lane >> 4;
  const float* xg = ws_in + OFF_X0 + (size_t)b * 5184;
  const float* rtab = ws_in + OFF_RT;
  const unsigned short* wb = (const unsigned short*)(ws_in + OFF_B);

  for (int u = tid; u < 5184; u += 256) XT[u] = xg[u];
  __syncthreads();                                               // 1
  if (tid < 81) {
    const float* xr = XT + tid*64;
    float sv = 0.f;
    for (int d = 0; d < 64; ++d) sv += xr[d];
    float mean = sv * (1.f/64.f);
    float sq = 0.f;
    for (int d = 0; d < 64; ++d) { float dv = xr[d]-mean; sq += dv*dv; }
    muv[tid] = mean;
    rsd[tid] = rsqrtf(sq*(1.f/64.f) + EPS);
  }
  __syncthreads();                                               // 2
  for (int u = tid; u < 5184; u += 256) {
    int s = u >> 6, d = u & 63;
    Hb[s*80 + d] = f2bf((XT[u] - muv[s])*rsd[s]*ln1g[l*64+d] + ln1b[l*64+d]);
  }
  for (int e = tid; e < 1200; e += 256) Hb[81*80 + e] = 0;       // zero rows 81..95
  __syncthreads();                                               // 3 (XT dead)

  for (int p = 0; p < 2; ++p) {
    float* QB = p ? P1 : P0;
    float* KB = p ? P2 : P1;
    float* VB = p ? P3 : P2;
    // projection GEMM [96x64]@[64x96] -> q/k/v for 2 heads
    const unsigned short* Bb = wb + WB_QKV + (size_t)(l*2 + p)*6144;
#pragma unroll
    for (int t = 0; t < 3; ++t) {
      int task = wid*3 + t;
      int Nt = task >> 1, mh = task & 1;
      f32x4 acc[3];
#pragma unroll
      for (int m3 = 0; m3 < 3; ++m3) acc[m3] = (f32x4){0.f,0.f,0.f,0.f};
#pragma unroll
      for (int Ks = 0; Ks < 2; ++Ks) {
        short8 bf = *(const short8*)(Bb + (size_t)(Nt*16 + lane15)*64 + Ks*32 + kgrp*8);
#pragma unroll
        for (int m3 = 0; m3 < 3; ++m3) {
          int r = (mh*3 + m3)*16 + lane15;
          short8 af = *(const short8*)(Hb + r*80 + Ks*32 + kgrp*8);
          acc[m3] = __builtin_amdgcn_mfma_f32_16x16x32_bf16(af, bf, acc[m3], 0, 0, 0);
        }
      }
      int col = Nt*16 + lane15;
      int m = col >> 5, idx = col & 31;
      float* dst = (m==0) ? QB : (m==1) ? KB : VB;
#pragma unroll
      for (int m3 = 0; m3 < 3; ++m3) {
#pragma unroll
        for (int r4 = 0; r4 < 4; ++r4) {
          int s = (mh*3 + m3)*16 + kgrp*4 + r4;
          if (s < 81) dst[s*34 + idx] = acc[m3][r4];
        }
      }
    }
    __syncthreads();                                             // 4 / 7
    for (int u = tid; u < 2592; u += 256) {
      int m = u / 1296;
      int rem = u - m*1296;
      int h2 = rem / 648;
      int r2 = rem - h2*648;
      int pp = r2 & 7, s = r2 >> 3;
      const float* rt = rtab + (m*648 + s*8 + pp)*2;
      float cu = rt[0], su = rt[1];
      float* ptr = (m ? KB : QB) + s*34 + h2*16 + 2*pp;
      float a = ptr[0], bb2 = ptr[1];
      ptr[0] = a*cu - bb2*su;
      ptr[1] = bb2*cu + a*su;
    }
    __syncthreads();                                             // 5 / 8
    if (tid < 162) {
      int h2 = tid & 1, s = tid >> 1;
      int hd = 2*p + h2;
      float g = 1.f - expf(-3.4657359f + (float)hd * (-0.92419624f));
      float lg = log2f(g);
      float q[16];
#pragma unroll
      for (int k = 0; k < 16; ++k) q[k] = QB[s*34 + h2*16 + k];
      float yh[16];
#pragma unroll
      for (int v = 0; v < 16; ++v) yh[v] = 0.f;
      for (int tt = 0; tt <= s; ++tt) {
        const float* Kr = KB + tt*34 + h2*16;
        float a = 0.f;
#pragma unroll
        for (int k = 0; k < 16; ++k) a = fmaf(q[k], Kr[k], a);
        a *= exp2f((float)(s - tt) * lg);
        const float* Vr = VB + tt*34 + h2*16;
#pragma unroll
        for (int v = 0; v < 16; ++v) yh[v] = fmaf(a, Vr[v], yh[v]);
      }
      float sv = 0.f;
#pragma unroll
      for (int v = 0; v < 16; ++v) sv += yh[v];
      float mean = sv * (1.f/16.f);
      float sq = 0.f;
#pragma unroll
      for (int v = 0; v < 16; ++v) { float dv = yh[v]-mean; sq += dv*dv; }
      float rstd = rsqrtf(sq*(1.f/16.f) + EPS);
#pragma unroll
      for (int v = 0; v < 16; ++v) {
        int col = hd*16 + v;
        QB[s*34 + h2*16 + v] = (yh[v]-mean)*rstd*gng[l*64+col] + gnb[l*64+col];
      }
    }
    __syncthreads();                                             // 6 / 9
  }
  // P0 = gn heads 0,1; P1 = gn heads 2,3; P2/P3 dead -> Zb

  // gate: Z = silu(H@wg) * gn -> Zb bf16 ; zero rows 81..95
  {
    for (int e = tid; e < 1200; e += 256) Zb[81*80 + e] = 0;
    const unsigned short* Gb = wb + WB_WG + (size_t)l*4096;
    f32x4 acc[6];
#pragma unroll
    for (int mt = 0; mt < 6; ++mt) acc[mt] = (f32x4){0.f,0.f,0.f,0.f};
#pragma unroll
    for (int Ks = 0; Ks < 2; ++Ks) {
      short8 bf = *(const short8*)(Gb + (size_t)(wid*16 + lane15)*64 + Ks*32 + kgrp*8);
#pragma unroll
      for (int mt = 0; mt < 6; ++mt) {
        short8 af = *(const short8*)(Hb + (mt*16 + lane15)*80 + Ks*32 + kgrp*8);
        acc[mt] = __builtin_amdgcn_mfma_f32_16x16x32_bf16(af, bf, acc[mt], 0, 0, 0);
      }
    }
    int col = wid*16 + lane15;
    const float* gnb_ = (col < 32) ? P0 : P1;
#pragma unroll
    for (int mt = 0; mt < 6; ++mt) {
#pragma unroll
      for (int r4 = 0; r4 < 4; ++r4) {
        int s = mt*16 + kgrp*4 + r4;
        if (s < 81) {
          float g = acc[mt][r4];
          float sig = 1.f/(1.f+expf(-g));
          Zb[s*80 + col] = f2bf(g*sig*gnb_[s*34 + (col & 31)]);
        }
      }
    }
  }
  __syncthreads();                                               // 10

  // wo: y = Z@wo + x -> global
  {
    const unsigned short* Ob = wb + WB_WO + (size_t)l*4096;
    float* yg = ws + OFF_Y + (size_t)b * 5184;
    f32x4 acc[6];
#pragma unroll
    for (int mt = 0; mt < 6; ++mt) acc[mt] = (f32x4){0.f,0.f,0.f,0.f};
#pragma unroll
    for (int Ks = 0; Ks < 2; ++Ks) {
      short8 bf = *(const short8*)(Ob + (size_t)(wid*16 + lane15)*64 + Ks*32 + kgrp*8);
#pragma unroll
      for (int mt = 0; mt < 6; ++mt) {
        short8 af = *(const short8*)(Zb + (mt*16 + lane15)*80 + Ks*32 + kgrp*8);
        acc[mt] = __builtin_amdgcn_mfma_f32_16x16x32_bf16(af, bf, acc[mt], 0, 0, 0);
      }
    }
    int col = wid*16 + lane15;
#pragma unroll
    for (int mt = 0; mt < 6; ++mt) {
#pragma unroll
      for (int r4 = 0; r4 < 4; ++r4) {
        int s = mt*16 + kgrp*4 + r4;
        if (s < 81) {
          int u = s*64 + col;
          yg[u] = acc[mt][r4] + xg[u];
        }
      }
    }
  }
}

// ---------------- ff_layer v5: MFMA fw1/fw2 ----------------
// sm floats: H2b(ush[96][80])=3840 | F1b(ush[96][144])=6912 | muv 81 | rsd 81
// XT fp32 overlays F1b.
__global__ __launch_bounds__(256) void ff_layer(const float* ws_in, float* ws,
    const float* fb1, const float* fb2, const float* ln2g, const float* ln2b, int l)
{
  __shared__ __align__(16) float sm[10914];
  unsigned short* H2b = (unsigned short*)sm;       // [96][80]
  unsigned short* F1b = (unsigned short*)(sm + 3840);  // [96][144]
  float* XT = sm + 3840;                           // [81][64] overlay F1b
  float* muv = sm + 10752;
  float* rsd = sm + 10833;
  const int tid  = threadIdx.x;
  const int b    = blockIdx.x;
  const int wid  = tid >> 6;
  const int lane = tid & 63;
  const int lane15 = lane & 15;
  const int kgrp   = lane >> 4;
  const float* yg = ws_in + OFF_Y + (size_t)b * 5184;
  const unsigned short* wb = (const unsigned short*)(ws_in + OFF_B);

  for (int u = tid; u < 5184; u += 256) XT[u] = yg[u];
  __syncthreads();
  if (tid < 81) {
    const float* xr = XT + tid*64;
    float sv = 0.f;
    for (int d = 0; d < 64; ++d) sv += xr[d];
    float mean = sv * (1.f/64.f);
    float sq = 0.f;
    for (int d = 0; d < 64; ++d) { float dv = xr[d]-mean; sq += dv*dv; }
    muv[tid] = mean;
    rsd[tid] = rsqrtf(sq*(1.f/64.f) + EPS);
  }
  __syncthreads();
  for (int u = tid; u < 5184; u += 256) {
    int s = u >> 6, d = u & 63;
    H2b[s*80 + d] = f2bf((XT[u] - muv[s])*rsd[s]*ln2g[l*64+d] + ln2b[l*64+d]);
  }
  for (int e = tid; e < 1200; e += 256) H2b[81*80 + e] = 0;
  __syncthreads();                                   // XT dead

  // fw1: F1 = gelu(H2@fw1 + fb1) -> F1b bf16 [96][144]; zero rows 81..95
  {
    for (int e = tid; e < 2160; e += 256) F1b[81*144 + e] = 0;
    const unsigned short* Wb1 = wb + WB_FW1 + (size_t)l*8192;
#pragma unroll
    for (int t = 0; t < 4; ++t) {
      int task = wid*4 + t;
      int Nt = task >> 1, mh = task & 1;
      f32x4 acc[3];
#pragma unroll
      for (int m3 = 0; m3 < 3; ++m3) acc[m3] = (f32x4){0.f,0.f,0.f,0.f};
#pragma unroll
      for (int Ks = 0; Ks < 2; ++Ks) {
        short8 bf = *(const short8*)(Wb1 + (size_t)(Nt*16 + lane15)*64 + Ks*32 + kgrp*8);
#pragma unroll
        for (int m3 = 0; m3 < 3; ++m3) {
          int r = (mh*3 + m3)*16 + lane15;
          short8 af = *(const short8*)(H2b + r*80 + Ks*32 + kgrp*8);
          acc[m3] = __builtin_amdgcn_mfma_f32_16x16x32_bf16(af, bf, acc[m3], 0, 0, 0);
        }
      }
      int col = Nt*16 + lane15;
#pragma unroll
      for (int m3 = 0; m3 < 3; ++m3) {
#pragma unroll
        for (int r4 = 0; r4 < 4; ++r4) {
          int s = (mh*3 + m3)*16 + kgrp*4 + r4;
          if (s < 81) {
            float pp = acc[m3][r4] + fb1[l*128 + col];
            F1b[s*144 + col] = f2bf(0.5f*pp*(1.f + erff(pp*0.70710678118f)));
          }
        }
      }
    }
  }
  __syncthreads();

  // fw2: x' = F1@fw2 + fb2 + y -> global
  {
    const unsigned short* Wb2 = wb + WB_FW2 + (size_t)l*8192;
    float* xg = ws + OFF_X0 + (size_t)b * 5184;
    f32x4 acc[6];
#pragma unroll
    for (int mt = 0; mt < 6; ++mt) acc[mt] = (f32x4){0.f,0.f,0.f,0.f};
#pragma unroll
    for (int Ks = 0; Ks < 4; ++Ks) {
      short8 bf = *(const short8*)(Wb2 + (size_t)(wid*16 + lane15)*128 + Ks*32 + kgrp*8);
#pragma unroll
      for (int mt = 0; mt < 6; ++mt) {
        short8 af = *(const short8*)(F1b + (mt*16 + lane15)*144 + Ks*32 + kgrp*8);
        acc[mt] = __builtin_amdgcn_mfma_f32_16x16x32_bf16(af, bf, acc[mt], 0, 0, 0);
      }
    }
    int col = wid*16 + lane15;
#pragma unroll
    for (int mt = 0; mt < 6; ++mt) {
#pragma unroll
      for (int r4 = 0; r4 < 4; ++r4) {
        int s = mt*16 + kgrp*4 + r4;
        if (s < 81) {
          int u = s*64 + col;
          xg[u] = acc[mt][r4] + fb2[l*64 + col] + yg[u];
        }
      }
    }
  }
}

// ---------------- fcls: classifier ----------------
__global__ __launch_bounds__(256) void fcls(const float* ws_in, const float* nn1w,
                                            const float* nn1b, float* out) {
  __shared__ float red[256];
  const int tid = threadIdx.x;
  const int b = blockIdx.x;
  const float* Xr = ws_in + OFF_X0 + (size_t)b * 5184;
  int c = tid & 15, chunk = tid >> 4;
  int i0 = chunk * 324;
  float a = 0.f;
  for (int i = 0; i < 324; ++i)
    a = fmaf(Xr[i0+i], nn1w[(size_t)(i0+i)*16 + c], a);
  red[tid] = a;
  __syncthreads();
  if (tid < 16) {
    float s = nn1b[tid];
#pragma unroll
    for (int j = 0; j < 16; ++j) s += red[j*16 + tid];
    out[b*16 + tid] = s;
  }
}

// ---------------- launch ----------------
extern "C" void kernel_launch(void* const* d_in, const int* in_sizes, int n_in,
                              void* d_out, int out_size, void* d_ws, size_t ws_size,
                              hipStream_t stream) {
  const float* X    = (const float*)d_in[0];
  const float* c3w  = (const float*)d_in[1];
  const float* c3b  = (const float*)d_in[2];
  const float* bn3g = (const float*)d_in[3];
  const float* bn3b = (const float*)d_in[4];
  const float* c2w  = (const float*)d_in[5];
  const float* c2b  = (const float*)d_in[6];
  const float* bn2g = (const float*)d_in[7];
  const float* bn2b = (const float*)d_in[8];
  const float* wq   = (const float*)d_in[9];
  const float* wk   = (const float*)d_in[10];
  const float* wv   = (const float*)d_in[11];
  const float* wg   = (const float*)d_in[12];
  const float* wo   = (const float*)d_in[13];
  const float* gng  = (const float*)d_in[14];
  const float* gnb  = (const float*)d_in[15];
  const float* ln1g = (const float*)d_in[16];
  const float* ln1b = (const float*)d_in[17];
  const float* ln2g = (const float*)d_in[18];
  const float* ln2b = (const float*)d_in[19];
  const float* fw1  = (const float*)d_in[20];
  const float* fb1  = (const float*)d_in[21];
  const float* fw2  = (const float*)d_in[22];
  const float* fb2  = (const float*)d_in[23];
  const float* nn1w = (const float*)d_in[24];
  const float* nn1b = (const float*)d_in[25];
  float* ws = (float*)d_ws;
  float* out = (float*)d_out;

  // conv stage
  kd1_conv1<<<108416, 256, 0, stream>>>(X, c3w, c3b, ws);
  kd2_bn1part<<<8192, 256, 0, stream>>>(ws, ws);
  kd3_bn1fin<<<1, 64, 0, stream>>>(ws, bn3g, bn3b);
  kd5_conv2_mfma<<<1024, 256, 0, stream>>>(ws, c2w, c2b, ws);
  kd6_bn2part<<<1024, 64, 0, stream>>>(ws, ws);
  kd7_bn2fin<<<1, 64, 0, stream>>>(ws, bn2g, bn2b);
  k0rot<<<6, 256, 0, stream>>>(ws);
  kd8_tokens<<<20736, 256, 0, stream>>>(ws);
  k0pack<<<288, 256, 0, stream>>>(wq, wk, wv, wg, wo, fw1, fw2, ws);  // OFF_B dead after kd8

  // transformer layers (fused per-batch, MFMA)
  for (int l = 0; l < 2; ++l) {
    fa_layer<<<1024, 256, 0, stream>>>(ws, ws, ln1g, ln1b, gng, gnb, l);
    ff_layer<<<1024, 256, 0, stream>>>(ws, ws, fb1, fb2, ln2g, ln2b, l);
  }

  fcls<<<1024, 256, 0, stream>>>(ws, nn1w, nn1b, out);
}

// Round 13
// 591.683 us; speedup vs baseline: 4.7608x; 1.7187x over previous
//
#include <hip/hip_runtime.h>
#include <math.h>

#define EPS 1e-5f

// ---------------- float offsets in ws ----------------
#define OFF_A  0u          // conv1 out CHANNEL-LAST [1024][121][224] (dead after conv2)
#define OFF_X0 0u          // tokens x [1024][81][64]
#define OFF_Y  31850496u   // y [1024][81][64]
#define OFF_CP 31850496u   // kd2 BN1 partials [1024][448] (dead before fa writes Y)
#define OFF_WC 32374784u   // packed conv2 bf16 weights [64][9][224] ushort (64512 floats)
#define OFF_B  47775744u   // conv2 out; after kd8: packed bf16 transformer weights
#define OFF_P  53084160u   // BN2 partials (dead after kd7 -> rotary table)
#define OFF_RT 53084160u   // rotary table
#define OFF_ST 53215232u   // scale1[8] shift1[8] scale2[64] shift2[64]

// packed bf16 transformer weight offsets (ushort units, base = (ushort*)(ws+OFF_B))
#define WB_QKV 0u
#define WB_WG  24576u
#define WB_WO  32768u
#define WB_FW1 40960u
#define WB_FW2 57344u

typedef __attribute__((ext_vector_type(8))) short short8;
typedef __attribute__((ext_vector_type(4))) float f32x4;

__device__ inline unsigned short f2bf(float f) {
  unsigned int x = __float_as_uint(f);
  unsigned int r = x + 0x7fffu + ((x >> 16) & 1u);
  return (unsigned short)(r >> 16);
}

// ---------------- kd1 v2: conv3d + bias -> A channel-last [b][pos][ci] ----------------
__global__ __launch_bounds__(256) void kd1_conv1(const float* X, const float* c3w,
                                                 const float* c3b, float* ws) {
  __shared__ float Xi[5070];
  __shared__ float w3[216];
  int tid = threadIdx.x, b = blockIdx.x;
  for (int u = tid; u < 5070; u += 256) Xi[u] = X[(size_t)b*5070 + u];
  if (tid < 216) w3[tid] = c3w[tid];
  __syncthreads();
  float* Ao = ws + OFF_A + (size_t)b*27104;
  for (int e = tid; e < 27104; e += 256) {
    int pos = e / 224, ci = e - pos*224;
    int o1 = ci / 28, dd = ci - o1*28;
    int h = pos / 11, w = pos - h*11;
    float a = c3b[o1];
    const float* xb = Xi + dd*169 + h*13 + w;
    const float* wp = w3 + o1*27;
#pragma unroll
    for (int kd = 0; kd < 3; ++kd)
#pragma unroll
      for (int kh = 0; kh < 3; ++kh)
#pragma unroll
        for (int kw = 0; kw < 3; ++kw)
          a = fmaf(xb[kd*169 + kh*13 + kw], wp[kd*9 + kh*3 + kw], a);
    Ao[e] = a;
  }
}

// ---------------- kd2 v2: BN1 column partials per (b, ci) ----------------
__global__ __launch_bounds__(256) void kd2_bn1part(const float* ws_in, float* ws) {
  int b = blockIdx.x, c = threadIdx.x;
  if (c >= 224) return;
  const float* Ab = ws_in + OFF_A + (size_t)b*27104;
  float S = 0.f, Q = 0.f;
  for (int pos = 0; pos < 121; ++pos) {
    float v = Ab[pos*224 + c];
    S += v; Q += v*v;
  }
  ws[OFF_CP + b*448 + c]       = S;
  ws[OFF_CP + b*448 + 224 + c] = Q;
}

// ---------------- kd3 v2: BN1 finalize (1 block, 256 threads) ----------------
__global__ void kd3_bn1fin(const float* ws_in, float* ws,
                           const float* bn3g, const float* bn3b) {
  __shared__ float sS[256], sQ[256];
  int t = threadIdx.x;
  int o1 = t >> 5, j = t & 31;
  float S = 0.f, Q = 0.f;
  for (int b = j; b < 1024; b += 32) {
    const float* P = ws_in + OFF_CP + b*448 + o1*28;
    for (int dd = 0; dd < 28; ++dd) { S += P[dd]; Q += P[224 + dd]; }
  }
  sS[t] = S; sQ[t] = Q;
  __syncthreads();
  if (j == 0) {
    float Ss = 0.f, Qs = 0.f;
    for (int k = 0; k < 32; ++k) { Ss += sS[o1*32 + k]; Qs += sQ[o1*32 + k]; }
    float n = 3469312.f;
    float mean = Ss / n;
    float var = Qs / n - mean*mean;
    float sc = bn3g[o1] * rsqrtf(var + EPS);
    ws[OFF_ST + o1]     = sc;
    ws[OFF_ST + 8 + o1] = bn3b[o1] - mean*sc;
  }
}

// ---------------- k0wc: pack conv2 weights bf16 [oc][kpos][ci] ----------------
__global__ void k0wc(const float* c2w, float* ws) {
  int i = blockIdx.x*256 + threadIdx.x;
  if (i >= 129024) return;
  int ci = i % 224; int r = i / 224; int kpos = r % 9; int oc = r / 9;
  ((unsigned short*)(ws + OFF_WC))[i] = f2bf(c2w[oc*2016 + ci*9 + kpos]);
}

// ---------------- kd5 v3: conv2 MFMA, no im2col (channel-last A) ----------------
__global__ __launch_bounds__(256) void kd5_conv2_mfma(const float* ws_in, const float* c2b,
                                                      float* ws) {
  __shared__ unsigned short InT[121*232];   // 56.1 KB
  __shared__ float bn1s[224], bn1sh[224];
  const int tid  = threadIdx.x;
  const int b    = blockIdx.x;
  const int wid  = tid >> 6;
  const int lane = tid & 63;
  const int lane15 = lane & 15;
  const int kgrp   = lane >> 4;
  if (tid < 224) {
    int o1 = tid / 28;
    bn1s[tid]  = ws_in[OFF_ST + o1];
    bn1sh[tid] = ws_in[OFF_ST + 8 + o1];
  }
  __syncthreads();
  const float* Ab = ws_in + OFF_A + (size_t)b*27104;
  for (int e = tid; e < 27104; e += 256) {
    int pos = e / 224, ci = e - pos*224;
    float v = fmaxf(bn1s[ci]*Ab[e] + bn1sh[ci], 0.f);
    InT[pos*232 + ci] = f2bf(v);
  }
  __syncthreads();

  int r0[6];
#pragma unroll
  for (int mt = 0; mt < 6; ++mt) {
    int s = mt*16 + lane15; if (s > 80) s = 80;
    int y = s / 9;
    r0[mt] = y*11 + (s - y*9);
  }
  const unsigned short* wcb = (const unsigned short*)(ws_in + OFF_WC);
  const int col = wid*16 + lane15;
  f32x4 acc[6];
#pragma unroll
  for (int mt = 0; mt < 6; ++mt) acc[mt] = (f32x4){0.f,0.f,0.f,0.f};

  for (int kpos = 0; kpos < 9; ++kpos) {
    int ki = kpos / 3, kj = kpos - ki*3;
    int roff = ki*11 + kj;
    const unsigned short* wcp = wcb + ((size_t)col*9 + kpos)*224 + kgrp*8;
#pragma unroll
    for (int Ks = 0; Ks < 7; ++Ks) {
      short8 bf = *(const short8*)(wcp + Ks*32);
#pragma unroll
      for (int mt = 0; mt < 6; ++mt) {
        short8 af = *(const short8*)(InT + (r0[mt] + roff)*232 + Ks*32 + kgrp*8);
        acc[mt] = __builtin_amdgcn_mfma_f32_16x16x32_bf16(af, bf, acc[mt], 0, 0, 0);
      }
    }
  }
  float bias = c2b[col];
  float* Bb = ws + OFF_B + (size_t)b*5184 + col*81;
#pragma unroll
  for (int mt = 0; mt < 6; ++mt) {
#pragma unroll
    for (int r = 0; r < 4; ++r) {
      int s = mt*16 + kgrp*4 + r;
      if (s < 81) Bb[s] = acc[mt][r] + bias;
    }
  }
}

// ---------------- kd6: BN2 partials ----------------
__global__ void kd6_bn2part(const float* ws_in, float* ws) {
  int b = blockIdx.x, t = threadIdx.x;
  const float* Bb = ws_in + OFF_B + (size_t)b * 5184 + t * 81;
  float S = 0.f, Q = 0.f;
  for (int s = 0; s < 81; ++s) {
    float v = Bb[s];
    S += v; Q += v * v;
  }
  ws[OFF_P + b*128 + t]      = S;
  ws[OFF_P + b*128 + 64 + t] = Q;
}

// ---------------- kd7: BN2 finalize ----------------
__global__ void kd7_bn2fin(float* ws, const float* bn2g, const float* bn2b) {
  int t = threadIdx.x;
  float S = 0.f, Q = 0.f;
  for (int b = 0; b < 1024; ++b) {
    S += ws[OFF_P + b*128 + t];
    Q += ws[OFF_P + b*128 + 64 + t];
  }
  float n = 82944.f;
  float mean = S / n;
  float var = Q / n - mean * mean;
  float sc = bn2g[t] * rsqrtf(var + EPS);
  ws[OFF_ST + 16 + t] = sc;
  ws[OFF_ST + 80 + t] = bn2b[t] - mean * sc;
}

// ---------------- k0rot: rotary tables ----------------
__global__ void k0rot(float* ws) {
  int i = blockIdx.x * 256 + threadIdx.x;
  if (i >= 1296) return;
  int m = i / 648, r = i - m*648;
  int s = r >> 3, pp = r & 7;
  float scale = (2.f*pp + 6.4f) / 22.4f;
  float xs = powf(scale, (float)s / 512.f);
  float invf = powf(10000.f, -(float)pp / 8.f);
  float ang = (float)s * invf;
  float cx = cosf(ang), sn = sinf(ang);
  float cu = m ? cx/xs : cx*xs;
  float su = m ? sn/xs : sn*xs;
  ws[OFF_RT + i*2]     = cu;
  ws[OFF_RT + i*2 + 1] = su;
}

// ---------------- kd8: BN2 apply + relu + transpose -> X0 ----------------
__global__ __launch_bounds__(256) void kd8_tokens(float* ws) {
  int idx = blockIdx.x * 256 + threadIdx.x;
  if (idx >= 5308416) return;
  int o = idx % 64;
  int s = (idx / 64) % 81;
  int b = idx / 5184;
  float v = ws[OFF_ST + 16 + o] * ws[OFF_B + (size_t)b*5184 + o*81 + s] + ws[OFF_ST + 80 + o];
  ws[OFF_X0 + idx] = fmaxf(v, 0.f);
}

// ---------------- k0pack: bf16 col-major transformer weight pack into dead OFF_B ----------------
__global__ void k0pack(const float* wq, const float* wk, const float* wv,
                       const float* wg, const float* wo, const float* fw1,
                       const float* fw2, float* ws) {
  int i = blockIdx.x * 256 + threadIdx.x;
  unsigned short* wb = (unsigned short*)(ws + OFF_B);
  if (i < 24576) {                      // QKV: [(l*2+p)*96+col][k]
    int l = i / 12288, r = i % 12288;
    int p = r / 6144; r %= 6144;
    int col = r / 64, k = r % 64;
    int m = col >> 5, h2 = (col >> 4) & 1, kk = col & 15;
    const float* src = (m==0) ? wq : (m==1) ? wk : wv;
    wb[i] = f2bf(src[((l*4 + 2*p + h2)*64 + k)*16 + kk]);
  } else if (i < 32768) {               // WG
    int j = i - 24576;
    int l = j / 4096, col = (j / 64) & 63, k = j & 63;
    wb[i] = f2bf(wg[(l*64 + k)*64 + col]);
  } else if (i < 40960) {               // WO
    int j = i - 32768;
    int l = j / 4096, col = (j / 64) & 63, k = j & 63;
    wb[i] = f2bf(wo[(l*64 + k)*64 + col]);
  } else if (i < 57344) {               // FW1
    int j = i - 40960;
    int l = j / 8192, col = (j / 64) % 128, k = j & 63;
    wb[i] = f2bf(fw1[(l*64 + k)*128 + col]);
  } else if (i < 73728) {               // FW2
    int j = i - 57344;
    int l = j / 8192, col = (j / 128) & 63, k = j % 128;
    wb[i] = f2bf(fw2[(l*128 + k)*64 + col]);
  }
}

// ---------------- fa_layer v6: MFMA projections/gate/wo; scalar retention ----------------
__global__ __launch_bounds__(256) void fa_layer(const float* ws_in, float* ws,
    const float* ln1g, const float* ln1b, const float* gng, const float* gnb, int l)
{
  __shared__ __align__(16) float sm[15018];
  unsigned short* Hb = (unsigned short*)sm;       // [96][80]
  float* P0 = sm + 3840;
  float* P1 = sm + 6594;
  float* P2 = sm + 9348;
  float* P3 = sm + 12102;
  float* XT = sm + 3840;                          // [81][64] overlay P0/P1
  unsigned short* Zb = (unsigned short*)(sm + 9348);  // [96][80] overlay P2/P3
  float* muv = sm + 14856;
  float* rsd = sm + 14937;
  const int tid  = threadIdx.x;
  const int b    = blockIdx.x;
  const int wid  = tid >> 6;
  const int lane = tid & 63;
  const int lane15 = lane & 15;
  const int kgrp   = lane >> 4;
  const float* xg = ws_in + OFF_X0 + (size_t)b * 5184;
  const float* rtab = ws_in + OFF_RT;
  const unsigned short* wb = (const unsigned short*)(ws_in + OFF_B);

  for (int u = tid; u < 5184; u += 256) XT[u] = xg[u];
  __syncthreads();
  if (tid < 81) {
    const float* xr = XT + tid*64;
    float sv = 0.f;
    for (int d = 0; d < 64; ++d) sv += xr[d];
    float mean = sv * (1.f/64.f);
    float sq = 0.f;
    for (int d = 0; d < 64; ++d) { float dv = xr[d]-mean; sq += dv*dv; }
    muv[tid] = mean;
    rsd[tid] = rsqrtf(sq*(1.f/64.f) + EPS);
  }
  __syncthreads();
  for (int u = tid; u < 5184; u += 256) {
    int s = u >> 6, d = u & 63;
    Hb[s*80 + d] = f2bf((XT[u] - muv[s])*rsd[s]*ln1g[l*64+d] + ln1b[l*64+d]);
  }
  for (int e = tid; e < 1200; e += 256) Hb[81*80 + e] = 0;
  __syncthreads();

  for (int p = 0; p < 2; ++p) {
    float* QB = p ? P1 : P0;
    float* KB = p ? P2 : P1;
    float* VB = p ? P3 : P2;
    const unsigned short* Bb = wb + WB_QKV + (size_t)(l*2 + p)*6144;
#pragma unroll
    for (int t = 0; t < 3; ++t) {
      int task = wid*3 + t;
      int Nt = task >> 1, mh = task & 1;
      f32x4 acc[3];
#pragma unroll
      for (int m3 = 0; m3 < 3; ++m3) acc[m3] = (f32x4){0.f,0.f,0.f,0.f};
#pragma unroll
      for (int Ks = 0; Ks < 2; ++Ks) {
        short8 bf = *(const short8*)(Bb + (size_t)(Nt*16 + lane15)*64 + Ks*32 + kgrp*8);
#pragma unroll
        for (int m3 = 0; m3 < 3; ++m3) {
          int r = (mh*3 + m3)*16 + lane15;
          short8 af = *(const short8*)(Hb + r*80 + Ks*32 + kgrp*8);
          acc[m3] = __builtin_amdgcn_mfma_f32_16x16x32_bf16(af, bf, acc[m3], 0, 0, 0);
        }
      }
      int col = Nt*16 + lane15;
      int m = col >> 5, idx = col & 31;
      float* dst = (m==0) ? QB : (m==1) ? KB : VB;
#pragma unroll
      for (int m3 = 0; m3 < 3; ++m3) {
#pragma unroll
        for (int r4 = 0; r4 < 4; ++r4) {
          int s = (mh*3 + m3)*16 + kgrp*4 + r4;
          if (s < 81) dst[s*34 + idx] = acc[m3][r4];
        }
      }
    }
    __syncthreads();
    for (int u = tid; u < 2592; u += 256) {
      int m = u / 1296;
      int rem = u - m*1296;
      int h2 = rem / 648;
      int r2 = rem - h2*648;
      int pp = r2 & 7, s = r2 >> 3;
      const float* rt = rtab + (m*648 + s*8 + pp)*2;
      float cu = rt[0], su = rt[1];
      float* ptr = (m ? KB : QB) + s*34 + h2*16 + 2*pp;
      float a = ptr[0], bb2 = ptr[1];
      ptr[0] = a*cu - bb2*su;
      ptr[1] = bb2*cu + a*su;
    }
    __syncthreads();
    if (tid < 162) {
      int h2 = tid & 1, s = tid >> 1;
      int hd = 2*p + h2;
      float g = 1.f - expf(-3.4657359f + (float)hd * (-0.92419624f));
      float lg = log2f(g);
      float q[16];
#pragma unroll
      for (int k = 0; k < 16; ++k) q[k] = QB[s*34 + h2*16 + k];
      float yh[16];
#pragma unroll
      for (int v = 0; v < 16; ++v) yh[v] = 0.f;
      for (int tt = 0; tt <= s; ++tt) {
        const float* Kr = KB + tt*34 + h2*16;
        float a = 0.f;
#pragma unroll
        for (int k = 0; k < 16; ++k) a = fmaf(q[k], Kr[k], a);
        a *= exp2f((float)(s - tt) * lg);
        const float* Vr = VB + tt*34 + h2*16;
#pragma unroll
        for (int v = 0; v < 16; ++v) yh[v] = fmaf(a, Vr[v], yh[v]);
      }
      float sv = 0.f;
#pragma unroll
      for (int v = 0; v < 16; ++v) sv += yh[v];
      float mean = sv * (1.f/16.f);
      float sq = 0.f;
#pragma unroll
      for (int v = 0; v < 16; ++v) { float dv = yh[v]-mean; sq += dv*dv; }
      float rstd = rsqrtf(sq*(1.f/16.f) + EPS);
#pragma unroll
      for (int v = 0; v < 16; ++v) {
        int col = hd*16 + v;
        QB[s*34 + h2*16 + v] = (yh[v]-mean)*rstd*gng[l*64+col] + gnb[l*64+col];
      }
    }
    __syncthreads();
  }

  {
    for (int e = tid; e < 1200; e += 256) Zb[81*80 + e] = 0;
    const unsigned short* Gb = wb + WB_WG + (size_t)l*4096;
    f32x4 acc[6];
#pragma unroll
    for (int mt = 0; mt < 6; ++mt) acc[mt] = (f32x4){0.f,0.f,0.f,0.f};
#pragma unroll
    for (int Ks = 0; Ks < 2; ++Ks) {
      short8 bf = *(const short8*)(Gb + (size_t)(wid*16 + lane15)*64 + Ks*32 + kgrp*8);
#pragma unroll
      for (int mt = 0; mt < 6; ++mt) {
        short8 af = *(const short8*)(Hb + (mt*16 + lane15)*80 + Ks*32 + kgrp*8);
        acc[mt] = __builtin_amdgcn_mfma_f32_16x16x32_bf16(af, bf, acc[mt], 0, 0, 0);
      }
    }
    int col = wid*16 + lane15;
    const float* gnb_ = (col < 32) ? P0 : P1;
#pragma unroll
    for (int mt = 0; mt < 6; ++mt) {
#pragma unroll
      for (int r4 = 0; r4 < 4; ++r4) {
        int s = mt*16 + kgrp*4 + r4;
        if (s < 81) {
          float g = acc[mt][r4];
          float sig = 1.f/(1.f+expf(-g));
          Zb[s*80 + col] = f2bf(g*sig*gnb_[s*34 + (col & 31)]);
        }
      }
    }
  }
  __syncthreads();

  {
    const unsigned short* Ob = wb + WB_WO + (size_t)l*4096;
    float* yg = ws + OFF_Y + (size_t)b * 5184;
    f32x4 acc[6];
#pragma unroll
    for (int mt = 0; mt < 6; ++mt) acc[mt] = (f32x4){0.f,0.f,0.f,0.f};
#pragma unroll
    for (int Ks = 0; Ks < 2; ++Ks) {
      short8 bf = *(const short8*)(Ob + (size_t)(wid*16 + lane15)*64 + Ks*32 + kgrp*8);
#pragma unroll
      for (int mt = 0; mt < 6; ++mt) {
        short8 af = *(const short8*)(Zb + (mt*16 + lane15)*80 + Ks*32 + kgrp*8);
        acc[mt] = __builtin_amdgcn_mfma_f32_16x16x32_bf16(af, bf, acc[mt], 0, 0, 0);
      }
    }
    int col = wid*16 + lane15;
#pragma unroll
    for (int mt = 0; mt < 6; ++mt) {
#pragma unroll
      for (int r4 = 0; r4 < 4; ++r4) {
        int s = mt*16 + kgrp*4 + r4;
        if (s < 81) {
          int u = s*64 + col;
          yg[u] = acc[mt][r4] + xg[u];
        }
      }
    }
  }
}

// ---------------- ff_layer v5: MFMA fw1/fw2 ----------------
__global__ __launch_bounds__(256) void ff_layer(const float* ws_in, float* ws,
    const float* fb1, const float* fb2, const float* ln2g, const float* ln2b, int l)
{
  __shared__ __align__(16) float sm[10914];
  unsigned short* H2b = (unsigned short*)sm;       // [96][80]
  unsigned short* F1b = (unsigned short*)(sm + 3840);  // [96][144]
  float* XT = sm + 3840;
  float* muv = sm + 10752;
  float* rsd = sm + 10833;
  const int tid  = threadIdx.x;
  const int b    = blockIdx.x;
  const int wid  = tid >> 6;
  const int lane = tid & 63;
  const int lane15 = lane & 15;
  const int kgrp   = lane >> 4;
  const float* yg = ws_in + OFF_Y + (size_t)b * 5184;
  const unsigned short* wb = (const unsigned short*)(ws_in + OFF_B);

  for (int u = tid; u < 5184; u += 256) XT[u] = yg[u];
  __syncthreads();
  if (tid < 81) {
    const float* xr = XT + tid*64;
    float sv = 0.f;
    for (int d = 0; d < 64; ++d) sv += xr[d];
    float mean = sv * (1.f/64.f);
    float sq = 0.f;
    for (int d = 0; d < 64; ++d) { float dv = xr[d]-mean; sq += dv*dv; }
    muv[tid] = mean;
    rsd[tid] = rsqrtf(sq*(1.f/64.f) + EPS);
  }
  __syncthreads();
  for (int u = tid; u < 5184; u += 256) {
    int s = u >> 6, d = u & 63;
    H2b[s*80 + d] = f2bf((XT[u] - muv[s])*rsd[s]*ln2g[l*64+d] + ln2b[l*64+d]);
  }
  for (int e = tid; e < 1200; e += 256) H2b[81*80 + e] = 0;
  __syncthreads();

  {
    for (int e = tid; e < 2160; e += 256) F1b[81*144 + e] = 0;
    const unsigned short* Wb1 = wb + WB_FW1 + (size_t)l*8192;
#pragma unroll
    for (int t = 0; t < 4; ++t) {
      int task = wid*4 + t;
      int Nt = task >> 1, mh = task & 1;
      f32x4 acc[3];
#pragma unroll
      for (int m3 = 0; m3 < 3; ++m3) acc[m3] = (f32x4){0.f,0.f,0.f,0.f};
#pragma unroll
      for (int Ks = 0; Ks < 2; ++Ks) {
        short8 bf = *(const short8*)(Wb1 + (size_t)(Nt*16 + lane15)*64 + Ks*32 + kgrp*8);
#pragma unroll
        for (int m3 = 0; m3 < 3; ++m3) {
          int r = (mh*3 + m3)*16 + lane15;
          short8 af = *(const short8*)(H2b + r*80 + Ks*32 + kgrp*8);
          acc[m3] = __builtin_amdgcn_mfma_f32_16x16x32_bf16(af, bf, acc[m3], 0, 0, 0);
        }
      }
      int col = Nt*16 + lane15;
#pragma unroll
      for (int m3 = 0; m3 < 3; ++m3) {
#pragma unroll
        for (int r4 = 0; r4 < 4; ++r4) {
          int s = (mh*3 + m3)*16 + kgrp*4 + r4;
          if (s < 81) {
            float pp = acc[m3][r4] + fb1[l*128 + col];
            F1b[s*144 + col] = f2bf(0.5f*pp*(1.f + erff(pp*0.70710678118f)));
          }
        }
      }
    }
  }
  __syncthreads();

  {
    const unsigned short* Wb2 = wb + WB_FW2 + (size_t)l*8192;
    float* xg = ws + OFF_X0 + (size_t)b * 5184;
    f32x4 acc[6];
#pragma unroll
    for (int mt = 0; mt < 6; ++mt) acc[mt] = (f32x4){0.f,0.f,0.f,0.f};
#pragma unroll
    for (int Ks = 0; Ks < 4; ++Ks) {
      short8 bf = *(const short8*)(Wb2 + (size_t)(wid*16 + lane15)*128 + Ks*32 + kgrp*8);
#pragma unroll
      for (int mt = 0; mt < 6; ++mt) {
        short8 af = *(const short8*)(F1b + (mt*16 + lane15)*144 + Ks*32 + kgrp*8);
        acc[mt] = __builtin_amdgcn_mfma_f32_16x16x32_bf16(af, bf, acc[mt], 0, 0, 0);
      }
    }
    int col = wid*16 + lane15;
#pragma unroll
    for (int mt = 0; mt < 6; ++mt) {
#pragma unroll
      for (int r4 = 0; r4 < 4; ++r4) {
        int s = mt*16 + kgrp*4 + r4;
        if (s < 81) {
          int u = s*64 + col;
          xg[u] = acc[mt][r4] + fb2[l*64 + col] + yg[u];
        }
      }
    }
  }
}

// ---------------- fcls: classifier ----------------
__global__ __launch_bounds__(256) void fcls(const float* ws_in, const float* nn1w,
                                            const float* nn1b, float* out) {
  __shared__ float red[256];
  const int tid = threadIdx.x;
  const int b = blockIdx.x;
  const float* Xr = ws_in + OFF_X0 + (size_t)b * 5184;
  int c = tid & 15, chunk = tid >> 4;
  int i0 = chunk * 324;
  float a = 0.f;
  for (int i = 0; i < 324; ++i)
    a = fmaf(Xr[i0+i], nn1w[(size_t)(i0+i)*16 + c], a);
  red[tid] = a;
  __syncthreads();
  if (tid < 16) {
    float s = nn1b[tid];
#pragma unroll
    for (int j = 0; j < 16; ++j) s += red[j*16 + tid];
    out[b*16 + tid] = s;
  }
}

// ---------------- launch ----------------
extern "C" void kernel_launch(void* const* d_in, const int* in_sizes, int n_in,
                              void* d_out, int out_size, void* d_ws, size_t ws_size,
                              hipStream_t stream) {
  const float* X    = (const float*)d_in[0];
  const float* c3w  = (const float*)d_in[1];
  const float* c3b  = (const float*)d_in[2];
  const float* bn3g = (const float*)d_in[3];
  const float* bn3b = (const float*)d_in[4];
  const float* c2w  = (const float*)d_in[5];
  const float* c2b  = (const float*)d_in[6];
  const float* bn2g = (const float*)d_in[7];
  const float* bn2b = (const float*)d_in[8];
  const float* wq   = (const float*)d_in[9];
  const float* wk   = (const float*)d_in[10];
  const float* wv   = (const float*)d_in[11];
  const float* wg   = (const float*)d_in[12];
  const float* wo   = (const float*)d_in[13];
  const float* gng  = (const float*)d_in[14];
  const float* gnb  = (const float*)d_in[15];
  const float* ln1g = (const float*)d_in[16];
  const float* ln1b = (const float*)d_in[17];
  const float* ln2g = (const float*)d_in[18];
  const float* ln2b = (const float*)d_in[19];
  const float* fw1  = (const float*)d_in[20];
  const float* fb1  = (const float*)d_in[21];
  const float* fw2  = (const float*)d_in[22];
  const float* fb2  = (const float*)d_in[23];
  const float* nn1w = (const float*)d_in[24];
  const float* nn1b = (const float*)d_in[25];
  float* ws = (float*)d_ws;
  float* out = (float*)d_out;

  // conv stage (channel-last conv1)
  k0wc<<<504, 256, 0, stream>>>(c2w, ws);
  kd1_conv1<<<1024, 256, 0, stream>>>(X, c3w, c3b, ws);
  kd2_bn1part<<<1024, 256, 0, stream>>>(ws, ws);
  kd3_bn1fin<<<1, 256, 0, stream>>>(ws, ws, bn3g, bn3b);
  kd5_conv2_mfma<<<1024, 256, 0, stream>>>(ws, c2b, ws);
  kd6_bn2part<<<1024, 64, 0, stream>>>(ws, ws);
  kd7_bn2fin<<<1, 64, 0, stream>>>(ws, bn2g, bn2b);
  k0rot<<<6, 256, 0, stream>>>(ws);
  kd8_tokens<<<20736, 256, 0, stream>>>(ws);
  k0pack<<<288, 256, 0, stream>>>(wq, wk, wv, wg, wo, fw1, fw2, ws);

  // transformer layers (fused per-batch, MFMA)
  for (int l = 0; l < 2; ++l) {
    fa_layer<<<1024, 256, 0, stream>>>(ws, ws, ln1g, ln1b, gng, gnb, l);
    ff_layer<<<1024, 256, 0, stream>>>(ws, ws, fb1, fb2, ln2g, ln2b, l);
  }

  fcls<<<1024, 256, 0, stream>>>(ws, nn1w, nn1b, out);
}

// Round 14
// 532.564 us; speedup vs baseline: 5.2893x; 1.1110x over previous
//
#include <hip/hip_runtime.h>
#include <math.h>

#define EPS 1e-5f

// ---------------- float offsets in ws ----------------
#define OFF_A  0u          // conv1 out bf16 CHANNEL-LAST ushort[1024][121][224] (dead after kd5)
#define OFF_X0 0u          // tokens x [1024][81][64] fp32 (written after A dead)
#define OFF_Y  31850496u   // y [1024][81][64]
#define OFF_CP 31850496u   // BN1 partials [1024][448] (dead before fa writes Y)
#define OFF_WC 32374784u   // packed conv2 bf16 weights [64][9][224] ushort
#define OFF_B  47775744u   // conv2 out; after kd8: packed bf16 transformer weights
#define OFF_P  53084160u   // BN2 partials (dead after kd7 -> rotary table)
#define OFF_RT 53084160u   // rotary table
#define OFF_ST 53215232u   // scale1[8] shift1[8] scale2[64] shift2[64]

// packed bf16 transformer weight offsets (ushort units, base = (ushort*)(ws+OFF_B))
#define WB_QKV 0u
#define WB_WG  24576u
#define WB_WO  32768u
#define WB_FW1 40960u
#define WB_FW2 57344u

typedef __attribute__((ext_vector_type(8))) short short8;
typedef __attribute__((ext_vector_type(4))) float f32x4;

__device__ inline unsigned short f2bf(float f) {
  unsigned int x = __float_as_uint(f);
  unsigned int r = x + 0x7fffu + ((x >> 16) & 1u);
  return (unsigned short)(r >> 16);
}
__device__ inline float bf2f(unsigned short h) {
  return __uint_as_float(((unsigned int)h) << 16);
}

// ---------------- kd1 v3: conv3d + bias -> A bf16 channel-last; fused BN1 partials ----------------
// thread = ci (224 active); 27 weights in regs; rolling 3-col window; coalesced stores.
__global__ __launch_bounds__(256) void kd1_conv1(const float* X, const float* c3w,
                                                 const float* c3b, float* ws) {
  __shared__ float Xi[5070];
  __shared__ float w3[216];
  int tid = threadIdx.x, b = blockIdx.x;
  for (int u = tid; u < 5070; u += 256) Xi[u] = X[(size_t)b*5070 + u];
  if (tid < 216) w3[tid] = c3w[tid];
  __syncthreads();
  if (tid >= 224) return;
  int o1 = tid / 28, dd = tid - o1*28;
  float wr[27];
#pragma unroll
  for (int k = 0; k < 27; ++k) wr[k] = w3[o1*27 + k];
  float bias = c3b[o1];
  unsigned short* Ao = (unsigned short*)(ws + OFF_A) + (size_t)b*27104;
  float S = 0.f, Q = 0.f;
  for (int h = 0; h < 11; ++h) {
    const float* base = Xi + dd*169 + h*13;
    float c0[9], c1[9], c2[9];
#pragma unroll
    for (int j = 0; j < 9; ++j) {
      int kd = j / 3, kh = j - kd*3;
      const float* rp = base + kd*169 + kh*13;
      c0[j] = rp[0]; c1[j] = rp[1]; c2[j] = rp[2];
    }
#pragma unroll
    for (int w = 0; w < 11; ++w) {
      float a = bias;
#pragma unroll
      for (int j = 0; j < 9; ++j) {
        a = fmaf(c0[j], wr[j*3+0], a);
        a = fmaf(c1[j], wr[j*3+1], a);
        a = fmaf(c2[j], wr[j*3+2], a);
      }
      Ao[(h*11 + w)*224 + tid] = f2bf(a);
      S += a; Q += a*a;
      if (w < 10) {
#pragma unroll
        for (int j = 0; j < 9; ++j) {
          int kd = j / 3, kh = j - kd*3;
          c0[j] = c1[j]; c1[j] = c2[j];
          c2[j] = base[kd*169 + kh*13 + w + 3];
        }
      }
    }
  }
  ws[OFF_CP + b*448 + tid]       = S;
  ws[OFF_CP + b*448 + 224 + tid] = Q;
}

// ---------------- kd3: BN1 finalize (1 block, 256 threads) ----------------
__global__ void kd3_bn1fin(const float* ws_in, float* ws,
                           const float* bn3g, const float* bn3b) {
  __shared__ float sS[256], sQ[256];
  int t = threadIdx.x;
  int o1 = t >> 5, j = t & 31;
  float S = 0.f, Q = 0.f;
  for (int b = j; b < 1024; b += 32) {
    const float* P = ws_in + OFF_CP + b*448 + o1*28;
    for (int dd = 0; dd < 28; ++dd) { S += P[dd]; Q += P[224 + dd]; }
  }
  sS[t] = S; sQ[t] = Q;
  __syncthreads();
  if (j == 0) {
    float Ss = 0.f, Qs = 0.f;
    for (int k = 0; k < 32; ++k) { Ss += sS[o1*32 + k]; Qs += sQ[o1*32 + k]; }
    float n = 3469312.f;
    float mean = Ss / n;
    float var = Qs / n - mean*mean;
    float sc = bn3g[o1] * rsqrtf(var + EPS);
    ws[OFF_ST + o1]     = sc;
    ws[OFF_ST + 8 + o1] = bn3b[o1] - mean*sc;
  }
}

// ---------------- k0wc: pack conv2 weights bf16 [oc][kpos][ci] ----------------
__global__ void k0wc(const float* c2w, float* ws) {
  int i = blockIdx.x*256 + threadIdx.x;
  if (i >= 129024) return;
  int ci = i % 224; int r = i / 224; int kpos = r % 9; int oc = r / 9;
  ((unsigned short*)(ws + OFF_WC))[i] = f2bf(c2w[oc*2016 + ci*9 + kpos]);
}

// ---------------- kd5 v4: conv2 MFMA, bf16 A in; fused BN2 partials out ----------------
__global__ __launch_bounds__(256) void kd5_conv2_mfma(const float* ws_in, const float* c2b,
                                                      float* ws) {
  __shared__ unsigned short InT[121*232];   // 56.1 KB
  __shared__ float bn1s[224], bn1sh[224];
  const int tid  = threadIdx.x;
  const int b    = blockIdx.x;
  const int wid  = tid >> 6;
  const int lane = tid & 63;
  const int lane15 = lane & 15;
  const int kgrp   = lane >> 4;
  if (tid < 224) {
    int o1 = tid / 28;
    bn1s[tid]  = ws_in[OFF_ST + o1];
    bn1sh[tid] = ws_in[OFF_ST + 8 + o1];
  }
  __syncthreads();
  const unsigned short* Ab = (const unsigned short*)(ws_in + OFF_A) + (size_t)b*27104;
  for (int e = tid; e < 27104; e += 256) {
    int pos = e / 224, ci = e - pos*224;
    float v = fmaxf(bn1s[ci]*bf2f(Ab[e]) + bn1sh[ci], 0.f);
    InT[pos*232 + ci] = f2bf(v);
  }
  __syncthreads();

  int r0[6];
#pragma unroll
  for (int mt = 0; mt < 6; ++mt) {
    int s = mt*16 + lane15; if (s > 80) s = 80;
    int y = s / 9;
    r0[mt] = y*11 + (s - y*9);
  }
  const unsigned short* wcb = (const unsigned short*)(ws_in + OFF_WC);
  const int col = wid*16 + lane15;
  f32x4 acc[6];
#pragma unroll
  for (int mt = 0; mt < 6; ++mt) acc[mt] = (f32x4){0.f,0.f,0.f,0.f};

  for (int kpos = 0; kpos < 9; ++kpos) {
    int ki = kpos / 3, kj = kpos - ki*3;
    int roff = ki*11 + kj;
    const unsigned short* wcp = wcb + ((size_t)col*9 + kpos)*224 + kgrp*8;
#pragma unroll
    for (int Ks = 0; Ks < 7; ++Ks) {
      short8 bf = *(const short8*)(wcp + Ks*32);
#pragma unroll
      for (int mt = 0; mt < 6; ++mt) {
        short8 af = *(const short8*)(InT + (r0[mt] + roff)*232 + Ks*32 + kgrp*8);
        acc[mt] = __builtin_amdgcn_mfma_f32_16x16x32_bf16(af, bf, acc[mt], 0, 0, 0);
      }
    }
  }
  // epilogue: bias + store B + fused BN2 partials (reduce over kgrp)
  float bias = c2b[col];
  float* Bb = ws + OFF_B + (size_t)b*5184 + col*81;
  float S = 0.f, Q = 0.f;
#pragma unroll
  for (int mt = 0; mt < 6; ++mt) {
#pragma unroll
    for (int r = 0; r < 4; ++r) {
      int s = mt*16 + kgrp*4 + r;
      if (s < 81) {
        float v = acc[mt][r] + bias;
        Bb[s] = v;
        S += v; Q += v*v;
      }
    }
  }
  S += __shfl_xor(S, 16); S += __shfl_xor(S, 32);
  Q += __shfl_xor(Q, 16); Q += __shfl_xor(Q, 32);
  if (kgrp == 0) {
    ws[OFF_P + b*128 + col]      = S;
    ws[OFF_P + b*128 + 64 + col] = Q;
  }
}

// ---------------- kd7: BN2 finalize ----------------
__global__ void kd7_bn2fin(float* ws, const float* bn2g, const float* bn2b) {
  int t = threadIdx.x;
  float S = 0.f, Q = 0.f;
  for (int b = 0; b < 1024; ++b) {
    S += ws[OFF_P + b*128 + t];
    Q += ws[OFF_P + b*128 + 64 + t];
  }
  float n = 82944.f;
  float mean = S / n;
  float var = Q / n - mean * mean;
  float sc = bn2g[t] * rsqrtf(var + EPS);
  ws[OFF_ST + 16 + t] = sc;
  ws[OFF_ST + 80 + t] = bn2b[t] - mean * sc;
}

// ---------------- k0rot: rotary tables ----------------
__global__ void k0rot(float* ws) {
  int i = blockIdx.x * 256 + threadIdx.x;
  if (i >= 1296) return;
  int m = i / 648, r = i - m*648;
  int s = r >> 3, pp = r & 7;
  float scale = (2.f*pp + 6.4f) / 22.4f;
  float xs = powf(scale, (float)s / 512.f);
  float invf = powf(10000.f, -(float)pp / 8.f);
  float ang = (float)s * invf;
  float cx = cosf(ang), sn = sinf(ang);
  float cu = m ? cx/xs : cx*xs;
  float su = m ? sn/xs : sn*xs;
  ws[OFF_RT + i*2]     = cu;
  ws[OFF_RT + i*2 + 1] = su;
}

// ---------------- kd8: BN2 apply + relu + transpose -> X0 ----------------
__global__ __launch_bounds__(256) void kd8_tokens(float* ws) {
  int idx = blockIdx.x * 256 + threadIdx.x;
  if (idx >= 5308416) return;
  int o = idx % 64;
  int s = (idx / 64) % 81;
  int b = idx / 5184;
  float v = ws[OFF_ST + 16 + o] * ws[OFF_B + (size_t)b*5184 + o*81 + s] + ws[OFF_ST + 80 + o];
  ws[OFF_X0 + idx] = fmaxf(v, 0.f);
}

// ---------------- k0pack: bf16 col-major transformer weight pack into dead OFF_B ----------------
__global__ void k0pack(const float* wq, const float* wk, const float* wv,
                       const float* wg, const float* wo, const float* fw1,
                       const float* fw2, float* ws) {
  int i = blockIdx.x * 256 + threadIdx.x;
  unsigned short* wb = (unsigned short*)(ws + OFF_B);
  if (i < 24576) {                      // QKV: [(l*2+p)*96+col][k]
    int l = i / 12288, r = i % 12288;
    int p = r / 6144; r %= 6144;
    int col = r / 64, k = r % 64;
    int m = col >> 5, h2 = (col >> 4) & 1, kk = col & 15;
    const float* src = (m==0) ? wq : (m==1) ? wk : wv;
    wb[i] = f2bf(src[((l*4 + 2*p + h2)*64 + k)*16 + kk]);
  } else if (i < 32768) {               // WG
    int j = i - 24576;
    int l = j / 4096, col = (j / 64) & 63, k = j & 63;
    wb[i] = f2bf(wg[(l*64 + k)*64 + col]);
  } else if (i < 40960) {               // WO
    int j = i - 32768;
    int l = j / 4096, col = (j / 64) & 63, k = j & 63;
    wb[i] = f2bf(wo[(l*64 + k)*64 + col]);
  } else if (i < 57344) {               // FW1
    int j = i - 40960;
    int l = j / 8192, col = (j / 64) % 128, k = j & 63;
    wb[i] = f2bf(fw1[(l*64 + k)*128 + col]);
  } else if (i < 73728) {               // FW2
    int j = i - 57344;
    int l = j / 8192, col = (j / 128) & 63, k = j % 128;
    wb[i] = f2bf(fw2[(l*128 + k)*64 + col]);
  }
}

// ---------------- fa_layer v6: MFMA projections/gate/wo; scalar retention ----------------
__global__ __launch_bounds__(256) void fa_layer(const float* ws_in, float* ws,
    const float* ln1g, const float* ln1b, const float* gng, const float* gnb, int l)
{
  __shared__ __align__(16) float sm[15018];
  unsigned short* Hb = (unsigned short*)sm;       // [96][80]
  float* P0 = sm + 3840;
  float* P1 = sm + 6594;
  float* P2 = sm + 9348;
  float* P3 = sm + 12102;
  float* XT = sm + 3840;                          // [81][64] overlay P0/P1
  unsigned short* Zb = (unsigned short*)(sm + 9348);  // [96][80] overlay P2/P3
  float* muv = sm + 14856;
  float* rsd = sm + 14937;
  const int tid  = threadIdx.x;
  const int b    = blockIdx.x;
  const int wid  = tid >> 6;
  const int lane = tid & 63;
  const int lane15 = lane & 15;
  const int kgrp   = lane >> 4;
  const float* xg = ws_in + OFF_X0 + (size_t)b * 5184;
  const float* rtab = ws_in + OFF_RT;
  const unsigned short* wb = (const unsigned short*)(ws_in + OFF_B);

  for (int u = tid; u < 5184; u += 256) XT[u] = xg[u];
  __syncthreads();
  if (tid < 81) {
    const float* xr = XT + tid*64;
    float sv = 0.f;
    for (int d = 0; d < 64; ++d) sv += xr[d];
    float mean = sv * (1.f/64.f);
    float sq = 0.f;
    for (int d = 0; d < 64; ++d) { float dv = xr[d]-mean; sq += dv*dv; }
    muv[tid] = mean;
    rsd[tid] = rsqrtf(sq*(1.f/64.f) + EPS);
  }
  __syncthreads();
  for (int u = tid; u < 5184; u += 256) {
    int s = u >> 6, d = u & 63;
    Hb[s*80 + d] = f2bf((XT[u] - muv[s])*rsd[s]*ln1g[l*64+d] + ln1b[l*64+d]);
  }
  for (int e = tid; e < 1200; e += 256) Hb[81*80 + e] = 0;
  __syncthreads();

  for (int p = 0; p < 2; ++p) {
    float* QB = p ? P1 : P0;
    float* KB = p ? P2 : P1;
    float* VB = p ? P3 : P2;
    const unsigned short* Bb = wb + WB_QKV + (size_t)(l*2 + p)*6144;
#pragma unroll
    for (int t = 0; t < 3; ++t) {
      int task = wid*3 + t;
      int Nt = task >> 1, mh = task & 1;
      f32x4 acc[3];
#pragma unroll
      for (int m3 = 0; m3 < 3; ++m3) acc[m3] = (f32x4){0.f,0.f,0.f,0.f};
#pragma unroll
      for (int Ks = 0; Ks < 2; ++Ks) {
        short8 bf = *(const short8*)(Bb + (size_t)(Nt*16 + lane15)*64 + Ks*32 + kgrp*8);
#pragma unroll
        for (int m3 = 0; m3 < 3; ++m3) {
          int r = (mh*3 + m3)*16 + lane15;
          short8 af = *(const short8*)(Hb + r*80 + Ks*32 + kgrp*8);
          acc[m3] = __builtin_amdgcn_mfma_f32_16x16x32_bf16(af, bf, acc[m3], 0, 0, 0);
        }
      }
      int col = Nt*16 + lane15;
      int m = col >> 5, idx = col & 31;
      float* dst = (m==0) ? QB : (m==1) ? KB : VB;
#pragma unroll
      for (int m3 = 0; m3 < 3; ++m3) {
#pragma unroll
        for (int r4 = 0; r4 < 4; ++r4) {
          int s = (mh*3 + m3)*16 + kgrp*4 + r4;
          if (s < 81) dst[s*34 + idx] = acc[m3][r4];
        }
      }
    }
    __syncthreads();
    for (int u = tid; u < 2592; u += 256) {
      int m = u / 1296;
      int rem = u - m*1296;
      int h2 = rem / 648;
      int r2 = rem - h2*648;
      int pp = r2 & 7, s = r2 >> 3;
      const float* rt = rtab + (m*648 + s*8 + pp)*2;
      float cu = rt[0], su = rt[1];
      float* ptr = (m ? KB : QB) + s*34 + h2*16 + 2*pp;
      float a = ptr[0], bb2 = ptr[1];
      ptr[0] = a*cu - bb2*su;
      ptr[1] = bb2*cu + a*su;
    }
    __syncthreads();
    if (tid < 162) {
      int h2 = tid & 1, s = tid >> 1;
      int hd = 2*p + h2;
      float g = 1.f - expf(-3.4657359f + (float)hd * (-0.92419624f));
      float lg = log2f(g);
      float q[16];
#pragma unroll
      for (int k = 0; k < 16; ++k) q[k] = QB[s*34 + h2*16 + k];
      float yh[16];
#pragma unroll
      for (int v = 0; v < 16; ++v) yh[v] = 0.f;
      for (int tt = 0; tt <= s; ++tt) {
        const float* Kr = KB + tt*34 + h2*16;
        float a = 0.f;
#pragma unroll
        for (int k = 0; k < 16; ++k) a = fmaf(q[k], Kr[k], a);
        a *= exp2f((float)(s - tt) * lg);
        const float* Vr = VB + tt*34 + h2*16;
#pragma unroll
        for (int v = 0; v < 16; ++v) yh[v] = fmaf(a, Vr[v], yh[v]);
      }
      float sv = 0.f;
#pragma unroll
      for (int v = 0; v < 16; ++v) sv += yh[v];
      float mean = sv * (1.f/16.f);
      float sq = 0.f;
#pragma unroll
      for (int v = 0; v < 16; ++v) { float dv = yh[v]-mean; sq += dv*dv; }
      float rstd = rsqrtf(sq*(1.f/16.f) + EPS);
#pragma unroll
      for (int v = 0; v < 16; ++v) {
        int col = hd*16 + v;
        QB[s*34 + h2*16 + v] = (yh[v]-mean)*rstd*gng[l*64+col] + gnb[l*64+col];
      }
    }
    __syncthreads();
  }

  {
    for (int e = tid; e < 1200; e += 256) Zb[81*80 + e] = 0;
    const unsigned short* Gb = wb + WB_WG + (size_t)l*4096;
    f32x4 acc[6];
#pragma unroll
    for (int mt = 0; mt < 6; ++mt) acc[mt] = (f32x4){0.f,0.f,0.f,0.f};
#pragma unroll
    for (int Ks = 0; Ks < 2; ++Ks) {
      short8 bf = *(const short8*)(Gb + (size_t)(wid*16 + lane15)*64 + Ks*32 + kgrp*8);
#pragma unroll
      for (int mt = 0; mt < 6; ++mt) {
        short8 af = *(const short8*)(Hb + (mt*16 + lane15)*80 + Ks*32 + kgrp*8);
        acc[mt] = __builtin_amdgcn_mfma_f32_16x16x32_bf16(af, bf, acc[mt], 0, 0, 0);
      }
    }
    int col = wid*16 + lane15;
    const float* gnb_ = (col < 32) ? P0 : P1;
#pragma unroll
    for (int mt = 0; mt < 6; ++mt) {
#pragma unroll
      for (int r4 = 0; r4 < 4; ++r4) {
        int s = mt*16 + kgrp*4 + r4;
        if (s < 81) {
          float g = acc[mt][r4];
          float sig = 1.f/(1.f+expf(-g));
          Zb[s*80 + col] = f2bf(g*sig*gnb_[s*34 + (col & 31)]);
        }
      }
    }
  }
  __syncthreads();

  {
    const unsigned short* Ob = wb + WB_WO + (size_t)l*4096;
    float* yg = ws + OFF_Y + (size_t)b * 5184;
    f32x4 acc[6];
#pragma unroll
    for (int mt = 0; mt < 6; ++mt) acc[mt] = (f32x4){0.f,0.f,0.f,0.f};
#pragma unroll
    for (int Ks = 0; Ks < 2; ++Ks) {
      short8 bf = *(const short8*)(Ob + (size_t)(wid*16 + lane15)*64 + Ks*32 + kgrp*8);
#pragma unroll
      for (int mt = 0; mt < 6; ++mt) {
        short8 af = *(const short8*)(Zb + (mt*16 + lane15)*80 + Ks*32 + kgrp*8);
        acc[mt] = __builtin_amdgcn_mfma_f32_16x16x32_bf16(af, bf, acc[mt], 0, 0, 0);
      }
    }
    int col = wid*16 + lane15;
#pragma unroll
    for (int mt = 0; mt < 6; ++mt) {
#pragma unroll
      for (int r4 = 0; r4 < 4; ++r4) {
        int s = mt*16 + kgrp*4 + r4;
        if (s < 81) {
          int u = s*64 + col;
          yg[u] = acc[mt][r4] + xg[u];
        }
      }
    }
  }
}

// ---------------- ff_layer v5: MFMA fw1/fw2 ----------------
__global__ __launch_bounds__(256) void ff_layer(const float* ws_in, float* ws,
    const float* fb1, const float* fb2, const float* ln2g, const float* ln2b, int l)
{
  __shared__ __align__(16) float sm[10914];
  unsigned short* H2b = (unsigned short*)sm;       // [96][80]
  unsigned short* F1b = (unsigned short*)(sm + 3840);  // [96][144]
  float* XT = sm + 3840;
  float* muv = sm + 10752;
  float* rsd = sm + 10833;
  const int tid  = threadIdx.x;
  const int b    = blockIdx.x;
  const int wid  = tid >> 6;
  const int lane = tid & 63;
  const int lane15 = lane & 15;
  const int kgrp   = lane >> 4;
  const float* yg = ws_in + OFF_Y + (size_t)b * 5184;
  const unsigned short* wb = (const unsigned short*)(ws_in + OFF_B);

  for (int u = tid; u < 5184; u += 256) XT[u] = yg[u];
  __syncthreads();
  if (tid < 81) {
    const float* xr = XT + tid*64;
    float sv = 0.f;
    for (int d = 0; d < 64; ++d) sv += xr[d];
    float mean = sv * (1.f/64.f);
    float sq = 0.f;
    for (int d = 0; d < 64; ++d) { float dv = xr[d]-mean; sq += dv*dv; }
    muv[tid] = mean;
    rsd[tid] = rsqrtf(sq*(1.f/64.f) + EPS);
  }
  __syncthreads();
  for (int u = tid; u < 5184; u += 256) {
    int s = u >> 6, d = u & 63;
    H2b[s*80 + d] = f2bf((XT[u] - muv[s])*rsd[s]*ln2g[l*64+d] + ln2b[l*64+d]);
  }
  for (int e = tid; e < 1200; e += 256) H2b[81*80 + e] = 0;
  __syncthreads();

  {
    for (int e = tid; e < 2160; e += 256) F1b[81*144 + e] = 0;
    const unsigned short* Wb1 = wb + WB_FW1 + (size_t)l*8192;
#pragma unroll
    for (int t = 0; t < 4; ++t) {
      int task = wid*4 + t;
      int Nt = task >> 1, mh = task & 1;
      f32x4 acc[3];
#pragma unroll
      for (int m3 = 0; m3 < 3; ++m3) acc[m3] = (f32x4){0.f,0.f,0.f,0.f};
#pragma unroll
      for (int Ks = 0; Ks < 2; ++Ks) {
        short8 bf = *(const short8*)(Wb1 + (size_t)(Nt*16 + lane15)*64 + Ks*32 + kgrp*8);
#pragma unroll
        for (int m3 = 0; m3 < 3; ++m3) {
          int r = (mh*3 + m3)*16 + lane15;
          short8 af = *(const short8*)(H2b + r*80 + Ks*32 + kgrp*8);
          acc[m3] = __builtin_amdgcn_mfma_f32_16x16x32_bf16(af, bf, acc[m3], 0, 0, 0);
        }
      }
      int col = Nt*16 + lane15;
#pragma unroll
      for (int m3 = 0; m3 < 3; ++m3) {
#pragma unroll
        for (int r4 = 0; r4 < 4; ++r4) {
          int s = (mh*3 + m3)*16 + kgrp*4 + r4;
          if (s < 81) {
            float pp = acc[m3][r4] + fb1[l*128 + col];
            F1b[s*144 + col] = f2bf(0.5f*pp*(1.f + erff(pp*0.70710678118f)));
          }
        }
      }
    }
  }
  __syncthreads();

  {
    const unsigned short* Wb2 = wb + WB_FW2 + (size_t)l*8192;
    float* xg = ws + OFF_X0 + (size_t)b * 5184;
    f32x4 acc[6];
#pragma unroll
    for (int mt = 0; mt < 6; ++mt) acc[mt] = (f32x4){0.f,0.f,0.f,0.f};
#pragma unroll
    for (int Ks = 0; Ks < 4; ++Ks) {
      short8 bf = *(const short8*)(Wb2 + (size_t)(wid*16 + lane15)*128 + Ks*32 + kgrp*8);
#pragma unroll
      for (int mt = 0; mt < 6; ++mt) {
        short8 af = *(const short8*)(F1b + (mt*16 + lane15)*144 + Ks*32 + kgrp*8);
        acc[mt] = __builtin_amdgcn_mfma_f32_16x16x32_bf16(af, bf, acc[mt], 0, 0, 0);
      }
    }
    int col = wid*16 + lane15;
#pragma unroll
    for (int mt = 0; mt < 6; ++mt) {
#pragma unroll
      for (int r4 = 0; r4 < 4; ++r4) {
        int s = mt*16 + kgrp*4 + r4;
        if (s < 81) {
          int u = s*64 + col;
          xg[u] = acc[mt][r4] + fb2[l*64 + col] + yg[u];
        }
      }
    }
  }
}

// ---------------- fcls: classifier ----------------
__global__ __launch_bounds__(256) void fcls(const float* ws_in, const float* nn1w,
                                            const float* nn1b, float* out) {
  __shared__ float red[256];
  const int tid = threadIdx.x;
  const int b = blockIdx.x;
  const float* Xr = ws_in + OFF_X0 + (size_t)b * 5184;
  int c = tid & 15, chunk = tid >> 4;
  int i0 = chunk * 324;
  float a = 0.f;
  for (int i = 0; i < 324; ++i)
    a = fmaf(Xr[i0+i], nn1w[(size_t)(i0+i)*16 + c], a);
  red[tid] = a;
  __syncthreads();
  if (tid < 16) {
    float s = nn1b[tid];
#pragma unroll
    for (int j = 0; j < 16; ++j) s += red[j*16 + tid];
    out[b*16 + tid] = s;
  }
}

// ---------------- launch ----------------
extern "C" void kernel_launch(void* const* d_in, const int* in_sizes, int n_in,
                              void* d_out, int out_size, void* d_ws, size_t ws_size,
                              hipStream_t stream) {
  const float* X    = (const float*)d_in[0];
  const float* c3w  = (const float*)d_in[1];
  const float* c3b  = (const float*)d_in[2];
  const float* bn3g = (const float*)d_in[3];
  const float* bn3b = (const float*)d_in[4];
  const float* c2w  = (const float*)d_in[5];
  const float* c2b  = (const float*)d_in[6];
  const float* bn2g = (const float*)d_in[7];
  const float* bn2b = (const float*)d_in[8];
  const float* wq   = (const float*)d_in[9];
  const float* wk   = (const float*)d_in[10];
  const float* wv   = (const float*)d_in[11];
  const float* wg   = (const float*)d_in[12];
  const float* wo   = (const float*)d_in[13];
  const float* gng  = (const float*)d_in[14];
  const float* gnb  = (const float*)d_in[15];
  const float* ln1g = (const float*)d_in[16];
  const float* ln1b = (const float*)d_in[17];
  const float* ln2g = (const float*)d_in[18];
  const float* ln2b = (const float*)d_in[19];
  const float* fw1  = (const float*)d_in[20];
  const float* fb1  = (const float*)d_in[21];
  const float* fw2  = (const float*)d_in[22];
  const float* fb2  = (const float*)d_in[23];
  const float* nn1w = (const float*)d_in[24];
  const float* nn1b = (const float*)d_in[25];
  float* ws = (float*)d_ws;
  float* out = (float*)d_out;

  // conv stage
  k0wc<<<504, 256, 0, stream>>>(c2w, ws);
  kd1_conv1<<<1024, 256, 0, stream>>>(X, c3w, c3b, ws);      // fused BN1 partials, bf16 A
  kd3_bn1fin<<<1, 256, 0, stream>>>(ws, ws, bn3g, bn3b);
  kd5_conv2_mfma<<<1024, 256, 0, stream>>>(ws, c2b, ws);     // fused BN2 partials
  kd7_bn2fin<<<1, 64, 0, stream>>>(ws, bn2g, bn2b);
  k0rot<<<6, 256, 0, stream>>>(ws);
  kd8_tokens<<<20736, 256, 0, stream>>>(ws);
  k0pack<<<288, 256, 0, stream>>>(wq, wk, wv, wg, wo, fw1, fw2, ws);

  // transformer layers (fused per-batch, MFMA)
  for (int l = 0; l < 2; ++l) {
    fa_layer<<<1024, 256, 0, stream>>>(ws, ws, ln1g, ln1b, gng, gnb, l);
    ff_layer<<<1024, 256, 0, stream>>>(ws, ws, fb1, fb2, ln2g, ln2b, l);
  }

  fcls<<<1024, 256, 0, stream>>>(ws, nn1w, nn1b, out);
}